// Round 1
// baseline (5818.757 us; speedup 1.0000x reference)
//
#include <hip/hip_runtime.h>
#include <math.h>

#define B_ 16
#define J_ 96
#define I_ 96
#define E_ 256
#define H_ 512
#define VS_ 32000
#define SJ_ 193
#define NROW (B_*J_)   // 1536

__device__ __forceinline__ float sigf(float x){ return 1.f/(1.f+__expf(-x)); }

__global__ void k_zero(float* p, int n){
  int i = blockIdx.x*blockDim.x + threadIdx.x;
  if (i < n) p[i] = 0.f;
}

__global__ void k_embed(const int* __restrict__ targets, const float* __restrict__ emb,
                        float* __restrict__ e_word){
  int row = blockIdx.x;
  int t = targets[row];
  e_word[(long long)row*E_ + threadIdx.x] = emb[(long long)t*E_ + threadIdx.x];
}

// Generic 64x64 tiled fp32 GEMM. EPI: 0 = C=A@B+bias, 1 = tanh(A@B+bias),
// 2 = per-row atomicAdd(rowsum, sum_n exp(A@B+bias)) (no C store).
template<int EPI>
__global__ void k_gemm(const float* __restrict__ A, int lda, long long sA,
                       const float* __restrict__ B, int ldb, long long sB,
                       float* __restrict__ C, int ldc, long long sC,
                       int M, int N, int K,
                       const float* __restrict__ bias, long long sBias,
                       float* __restrict__ rowsum)
{
  const int bz = blockIdx.z;
  A += (long long)bz*sA; B += (long long)bz*sB;
  if (C) C += (long long)bz*sC;
  if (bias) bias += (long long)bz*sBias;
  const int m0 = blockIdx.y*64, n0 = blockIdx.x*64;
  __shared__ float As[16][68];
  __shared__ float Bs[16][68];
  __shared__ float red[64][17];
  const int tid = threadIdx.x;         // 256
  const int tx = tid & 15, ty = tid >> 4;
  float acc[4][4] = {};
  for (int k0 = 0; k0 < K; k0 += 16){
    {
      const int kk = tid & 15, r0 = tid >> 4;
      #pragma unroll
      for (int i = 0; i < 4; i++){
        int rr = r0 + i*16, m = m0 + rr;
        As[kk][rr] = (m < M) ? A[(long long)m*lda + k0 + kk] : 0.f;
      }
    }
    {
      const int c = tid & 63, k4 = tid >> 6;
      #pragma unroll
      for (int i = 0; i < 4; i++){
        int kk = k4 + i*4, n = n0 + c;
        Bs[kk][c] = (n < N) ? B[(long long)(k0+kk)*ldb + n] : 0.f;
      }
    }
    __syncthreads();
    #pragma unroll
    for (int kk = 0; kk < 16; kk++){
      float a[4], b[4];
      #pragma unroll
      for (int i = 0; i < 4; i++) a[i] = As[kk][ty*4 + i];
      #pragma unroll
      for (int j = 0; j < 4; j++) b[j] = Bs[kk][tx*4 + j];
      #pragma unroll
      for (int i = 0; i < 4; i++)
        #pragma unroll
        for (int j = 0; j < 4; j++)
          acc[i][j] += a[i]*b[j];
    }
    __syncthreads();
  }
  if (EPI == 2){
    #pragma unroll
    for (int i = 0; i < 4; i++){
      float p = 0.f;
      #pragma unroll
      for (int j = 0; j < 4; j++){
        int n = n0 + tx*4 + j;
        if (n < N) p += __expf(acc[i][j] + (bias ? bias[n] : 0.f));
      }
      red[ty*4 + i][tx] = p;
    }
    __syncthreads();
    if (tid < 64){
      int m = m0 + tid;
      if (m < M){
        float s = 0.f;
        #pragma unroll
        for (int x = 0; x < 16; x++) s += red[tid][x];
        atomicAdd(&rowsum[m], s);
      }
    }
  } else {
    #pragma unroll
    for (int i = 0; i < 4; i++){
      int m = m0 + ty*4 + i;
      if (m >= M) continue;
      #pragma unroll
      for (int j = 0; j < 4; j++){
        int n = n0 + tx*4 + j;
        if (n >= N) continue;
        float v = acc[i][j] + (bias ? bias[n] : 0.f);
        if (EPI == 1) v = tanhf(v);
        C[(long long)m*ldc + n] = v;
      }
    }
  }
}

// One LSTM step, both directions fused. grid 64 x 256 threads.
// hbuf: [2 dir][2 buf][B][H], cbuf: [2 dir][B][H]
__global__ void k_lstm_step(const float* __restrict__ Xfw, const float* __restrict__ Xbw,
                            const float* __restrict__ Wfw, const float* __restrict__ Wbw,
                            float* __restrict__ hbuf, float* __restrict__ cbuf,
                            float* __restrict__ Hcat, int t)
{
  const int bx = blockIdx.x;             // 0..63
  const int dir = bx >> 5;
  const int rem = bx & 31;
  const int b = rem >> 1;
  const int u = (rem & 1)*256 + threadIdx.x;
  const int cur = t & 1, nxt = cur ^ 1;
  const int t_eff = dir ? (J_-1 - t) : t;
  const float* X = dir ? Xbw : Xfw;
  const float* W = (dir ? Wbw : Wfw) + (long long)E_*2048;   // h-part rows
  const float* hp = hbuf + ((long long)(dir*2 + cur)*B_ + b)*H_;
  __shared__ float hs[H_];
  hs[threadIdx.x]       = hp[threadIdx.x];
  hs[256 + threadIdx.x] = hp[256 + threadIdx.x];
  __syncthreads();
  const long long row = (long long)b*J_ + t_eff;
  float zi = X[row*2048 + 0*H_ + u];
  float zg = X[row*2048 + 1*H_ + u];
  float zf = X[row*2048 + 2*H_ + u];
  float zo = X[row*2048 + 3*H_ + u];
  #pragma unroll 4
  for (int k = 0; k < H_; k++){
    float hv = hs[k];
    const float* wr = W + (long long)k*2048;
    zi += hv * wr[u];
    zg += hv * wr[H_ + u];
    zf += hv * wr[2*H_ + u];
    zo += hv * wr[3*H_ + u];
  }
  float* cp = cbuf + ((long long)dir*B_ + b)*H_ + u;
  float c = *cp;
  c = sigf(zf + 1.f)*c + sigf(zi)*tanhf(zg);
  float h = sigf(zo)*tanhf(c);
  *cp = c;
  hbuf[((long long)(dir*2 + nxt)*B_ + b)*H_ + u] = h;
  Hcat[row*(2*H_) + dir*H_ + u] = h;
}

__global__ void k_tn(const int* __restrict__ tnull, const float* __restrict__ emb,
                     const float* __restrict__ W1, const float* __restrict__ b1,
                     float* __restrict__ tn){
  __shared__ float en[E_];
  int t = tnull[0];
  en[threadIdx.x] = emb[(long long)t*E_ + threadIdx.x];
  __syncthreads();
  int u = blockIdx.x*256 + threadIdx.x;
  float s = b1[u];
  for (int e = 0; e < E_; e++) s += en[e]*W1[(long long)e*H_ + u];
  tn[u] = tanhf(s);
}

__global__ void k_p0(const float* __restrict__ tn, const float* __restrict__ Wp,
                     const float* __restrict__ bp, float* __restrict__ p0){
  __shared__ float red[256];
  int tid = threadIdx.x;
  red[tid] = tn[tid]*Wp[tid] + tn[tid+256]*Wp[tid+256];
  __syncthreads();
  for (int w = 128; w > 0; w >>= 1){
    if (tid < w) red[tid] += red[tid+w];
    __syncthreads();
  }
  if (tid == 0) p0[0] = sigf(red[0] + bp[0])*0.3f;
}

__global__ void k_nullrow(const float* __restrict__ tn, const float* __restrict__ Wv,
                          const float* __restrict__ bv, float* __restrict__ lognull,
                          float* __restrict__ nullsum){
  __shared__ float tns[H_];
  __shared__ float red[256];
  int tid = threadIdx.x;
  tns[tid] = tn[tid]; tns[tid+256] = tn[tid+256];
  __syncthreads();
  int c = blockIdx.x*256 + tid;
  float s = bv[c];
  for (int k = 0; k < H_; k++) s += tns[k]*Wv[(long long)k*VS_ + c];
  lognull[c] = s;
  red[tid] = __expf(s);
  __syncthreads();
  for (int w = 128; w > 0; w >>= 1){
    if (tid < w) red[tid] += red[tid+w];
    __syncthreads();
  }
  if (tid == 0) atomicAdd(nullsum, red[0]);
}

__global__ void k_gather(const int* __restrict__ sources, const float* __restrict__ Wv,
                         const float* __restrict__ bv, float* __restrict__ WgT,
                         float* __restrict__ bg){
  int bk = blockIdx.x;           // b*H_ + k
  int b = bk >> 9, k = bk & 511;
  int i = threadIdx.x;
  if (i >= I_) return;
  int s = sources[b*I_ + i];
  WgT[((long long)b*H_ + k)*I_ + i] = Wv[(long long)k*VS_ + s];
  if (k == 0) bg[b*I_ + i] = bv[s];
}

__global__ void k_emission(const float* __restrict__ gl, const float* __restrict__ rowsum,
                           const float* __restrict__ lognull, const float* __restrict__ nullsum,
                           const int* __restrict__ sources, float* __restrict__ out_em){
  int bx = blockIdx.x;           // b*192 + jj
  int b = bx / 192, jj = bx % 192;
  int i = threadIdx.x;
  if (i >= I_) return;
  float v;
  if (jj < J_) v = __expf(gl[((long long)b*J_ + jj)*I_ + i]) / rowsum[b*J_ + jj];
  else { int s = sources[b*I_ + i]; v = __expf(lognull[s]) / nullsum[0]; }
  out_em[(long long)bx*I_ + i] = v;
}

__global__ void k_transition(const float* __restrict__ jlog, const float* __restrict__ p0p,
                             float* __restrict__ T, float* __restrict__ TL){
  int bx = blockIdx.x;           // b*J_ + j
  int b = bx / J_, j = bx % J_;
  int tid = threadIdx.x;         // 128
  __shared__ float ex[128];
  __shared__ float red[128];
  float e = 0.f;
  if (tid < 96) e = __expf(jlog[(long long)bx*SJ_ + (96 - j + tid)]);
  ex[tid] = e; red[tid] = e;
  __syncthreads();
  for (int w = 64; w > 0; w >>= 1){
    if (tid < w) red[tid] += red[tid+w];
    __syncthreads();
  }
  float p0 = p0p[0];
  float scale = (1.f - p0) / red[0];
  float lp0 = logf(p0);
  long long r0 = ((long long)b*192 + j)*192;
  long long r1 = ((long long)b*192 + j + 96)*192;
  for (int col = tid; col < 192; col += 128){
    float tv, lv;
    if (col < 96){ tv = ex[col]*scale; lv = logf(tv); }
    else { bool d = (col - 96) == j; tv = d ? p0 : 0.f; lv = d ? lp0 : 0.f; }
    T[r0 + col] = tv; T[r1 + col] = tv;
    TL[r0 + col] = lv; TL[r1 + col] = lv;
  }
}

extern "C" void kernel_launch(void* const* d_in, const int* in_sizes, int n_in,
                              void* d_out, int out_size, void* d_ws, size_t ws_size,
                              hipStream_t stream)
{
  const int* sources = (const int*)d_in[0];
  const int* targets = (const int*)d_in[1];
  const int* tnull   = (const int*)d_in[2];
  const float* emb   = (const float*)d_in[3];
  const float* Wfw   = (const float*)d_in[4];
  const float* bfw   = (const float*)d_in[5];
  const float* Wbw   = (const float*)d_in[6];
  const float* bbw   = (const float*)d_in[7];
  const float* Wl    = (const float*)d_in[8];
  const float* W1    = (const float*)d_in[9];
  const float* b1    = (const float*)d_in[10];
  const float* Wv    = (const float*)d_in[11];
  const float* bv    = (const float*)d_in[12];
  const float* Wj    = (const float*)d_in[13];
  const float* bj    = (const float*)d_in[14];
  const float* Wp    = (const float*)d_in[15];
  const float* bp    = (const float*)d_in[16];
  float* out = (float*)d_out;
  float* ws  = (float*)d_ws;

  long long off = 0;
  float* e_word = ws + off; off += (long long)NROW*E_;
  float* Xfw    = ws + off; off += (long long)NROW*2048;
  float* Xbw    = ws + off; off += (long long)NROW*2048;
  float* Hcat   = ws + off; off += (long long)NROW*1024;
  float* hbuf   = ws + off; off += 2*2*B_*H_;
  float* cbuf   = ws + off; off += 2*B_*H_;
  float* ts     = ws + off; off += (long long)NROW*E_;
  float* t1     = ws + off; off += (long long)NROW*H_;
  float* tn     = ws + off; off += H_;
  float* rowsum = ws + off; off += NROW;
  float* nullsum= ws + off; off += 1;
  float* p0     = ws + off; off += 1;
  float* gl     = ws + off; off += (long long)NROW*I_;
  float* WgT    = ws + off; off += (long long)B_*H_*I_;
  float* bg     = ws + off; off += B_*I_;
  float* lognull= ws + off; off += VS_;
  float* jlog   = ws + off; off += (long long)NROW*SJ_;

  float* out_em = out;
  float* out_T  = out + (long long)B_*192*96;
  float* out_TL = out_T + (long long)B_*192*192;

  // per-call init of accumulators / recurrent state
  int nz1 = 2*2*B_*H_ + 2*B_*H_;                  // hbuf + cbuf (contiguous)
  k_zero<<<(nz1+255)/256, 256, 0, stream>>>(hbuf, nz1);
  k_zero<<<7, 256, 0, stream>>>(rowsum, NROW + 1); // rowsum + nullsum (contiguous)

  k_embed<<<NROW, 256, 0, stream>>>(targets, emb, e_word);

  // input projections for both directions: [1536,256] @ [256,2048] + b
  dim3 gx(2048/64, NROW/64);
  k_gemm<0><<<gx, 256, 0, stream>>>(e_word, E_, 0, Wfw, 2048, 0, Xfw, 2048, 0,
                                    NROW, 2048, E_, bfw, 0, nullptr);
  k_gemm<0><<<gx, 256, 0, stream>>>(e_word, E_, 0, Wbw, 2048, 0, Xbw, 2048, 0,
                                    NROW, 2048, E_, bbw, 0, nullptr);

  for (int t = 0; t < J_; t++)
    k_lstm_step<<<64, 256, 0, stream>>>(Xfw, Xbw, Wfw, Wbw, hbuf, cbuf, Hcat, t);

  // ts = Hcat @ W_lstm   [1536,1024]@[1024,256]
  k_gemm<0><<<dim3(E_/64, NROW/64), 256, 0, stream>>>(Hcat, 2*H_, 0, Wl, E_, 0,
                                                      ts, E_, 0, NROW, E_, 2*H_,
                                                      nullptr, 0, nullptr);
  // t1 = tanh(ts @ W1 + b1)   [1536,256]@[256,512]
  k_gemm<1><<<dim3(H_/64, NROW/64), 256, 0, stream>>>(ts, E_, 0, W1, H_, 0,
                                                      t1, H_, 0, NROW, H_, E_,
                                                      b1, 0, nullptr);

  k_tn<<<2, 256, 0, stream>>>(tnull, emb, W1, b1, tn);
  k_p0<<<1, 256, 0, stream>>>(tn, Wp, bp, p0);
  k_nullrow<<<VS_/256, 256, 0, stream>>>(tn, Wv, bv, lognull, nullsum);
  k_gather<<<B_*H_, 128, 0, stream>>>(sources, Wv, bv, WgT, bg);

  // row-wise sum of exp(t1 @ Wv + bv) over 32000 cols (fused epilogue)
  k_gemm<2><<<dim3(VS_/64, NROW/64), 256, 0, stream>>>(t1, H_, 0, Wv, VS_, 0,
                                                       nullptr, 0, 0, NROW, VS_, H_,
                                                       bv, 0, rowsum);
  // gathered logits: per-batch [96,512]@[512,96] + gathered bias
  k_gemm<0><<<dim3(2, 2, B_), 256, 0, stream>>>(t1, H_, (long long)J_*H_,
                                                WgT, I_, (long long)H_*I_,
                                                gl, I_, (long long)J_*I_,
                                                J_, I_, H_, bg, I_, nullptr);
  // jump logits: [1536,512]@[512,193] + bj
  k_gemm<0><<<dim3(4, NROW/64), 256, 0, stream>>>(t1, H_, 0, Wj, SJ_, 0,
                                                  jlog, SJ_, 0, NROW, SJ_, H_,
                                                  bj, 0, nullptr);

  k_emission<<<B_*192, 128, 0, stream>>>(gl, rowsum, lognull, nullsum, sources, out_em);
  k_transition<<<NROW, 128, 0, stream>>>(jlog, p0, out_T, out_TL);
}

// Round 2
// 2843.815 us; speedup vs baseline: 2.0461x; 2.0461x over previous
//
#include <hip/hip_runtime.h>
#include <math.h>

#define B_ 16
#define J_ 96
#define I_ 96
#define E_ 256
#define H_ 512
#define VS_ 32000
#define SJ_ 193
#define NROW (B_*J_)   // 1536

typedef __attribute__((ext_vector_type(8))) short short8;
typedef __attribute__((ext_vector_type(4))) float f32x4;

__device__ __forceinline__ float sigf(float x){ return 1.f/(1.f+__expf(-x)); }

__device__ __forceinline__ unsigned short f2bf(float x){
  unsigned int u = __float_as_uint(x);
  unsigned int r = (u + 0x7FFFu + ((u>>16)&1u)) >> 16;
  return (unsigned short)r;
}

#define ASYNC16(gp, lp) __builtin_amdgcn_global_load_lds( \
    (const __attribute__((address_space(1))) unsigned int*)(gp), \
    (__attribute__((address_space(3))) unsigned int*)(lp), 16, 0, 0)

__global__ void k_zero(float* p, int n){
  int i = blockIdx.x*blockDim.x + threadIdx.x;
  if (i < n) p[i] = 0.f;
}

__global__ void k_embed(const int* __restrict__ targets, const float* __restrict__ emb,
                        float* __restrict__ e_word){
  int row = blockIdx.x;
  int t = targets[row];
  e_word[(long long)row*E_ + threadIdx.x] = emb[(long long)t*E_ + threadIdx.x];
}

// Generic 64x64 tiled fp32 GEMM. EPI: 0 = C=A@B+bias, 1 = tanh(A@B+bias) (+bf16 copy)
template<int EPI>
__global__ void k_gemm(const float* __restrict__ A, int lda, long long sA,
                       const float* __restrict__ B, int ldb, long long sB,
                       float* __restrict__ C, int ldc, long long sC,
                       int M, int N, int K,
                       const float* __restrict__ bias, long long sBias,
                       unsigned short* __restrict__ Ch)
{
  const int bz = blockIdx.z;
  A += (long long)bz*sA; B += (long long)bz*sB;
  if (C) C += (long long)bz*sC;
  if (bias) bias += (long long)bz*sBias;
  const int m0 = blockIdx.y*64, n0 = blockIdx.x*64;
  __shared__ float As[16][68];
  __shared__ float Bs[16][68];
  const int tid = threadIdx.x;         // 256
  const int tx = tid & 15, ty = tid >> 4;
  float acc[4][4] = {};
  for (int k0 = 0; k0 < K; k0 += 16){
    {
      const int kk = tid & 15, r0 = tid >> 4;
      #pragma unroll
      for (int i = 0; i < 4; i++){
        int rr = r0 + i*16, m = m0 + rr;
        As[kk][rr] = (m < M) ? A[(long long)m*lda + k0 + kk] : 0.f;
      }
    }
    {
      const int c = tid & 63, k4 = tid >> 6;
      #pragma unroll
      for (int i = 0; i < 4; i++){
        int kk = k4 + i*4, n = n0 + c;
        Bs[kk][c] = (n < N) ? B[(long long)(k0+kk)*ldb + n] : 0.f;
      }
    }
    __syncthreads();
    #pragma unroll
    for (int kk = 0; kk < 16; kk++){
      float a[4], b[4];
      #pragma unroll
      for (int i = 0; i < 4; i++) a[i] = As[kk][ty*4 + i];
      #pragma unroll
      for (int j = 0; j < 4; j++) b[j] = Bs[kk][tx*4 + j];
      #pragma unroll
      for (int i = 0; i < 4; i++)
        #pragma unroll
        for (int j = 0; j < 4; j++)
          acc[i][j] += a[i]*b[j];
    }
    __syncthreads();
  }
  #pragma unroll
  for (int i = 0; i < 4; i++){
    int m = m0 + ty*4 + i;
    if (m >= M) continue;
    #pragma unroll
    for (int j = 0; j < 4; j++){
      int n = n0 + tx*4 + j;
      if (n >= N) continue;
      float v = acc[i][j] + (bias ? bias[n] : 0.f);
      if (EPI == 1) v = tanhf(v);
      C[(long long)m*ldc + n] = v;
      if (EPI == 1 && Ch) Ch[(long long)m*ldc + n] = f2bf(v);
    }
  }
}

// Persistent bi-LSTM: 128 blocks (64 per dir), each owns 8 hidden units.
// W_h slice staged in LDS as packed bf16 pairs (32KB) + full h staged per step (32KB).
__global__ __launch_bounds__(256, 1) void k_lstm_persist(
    const float* __restrict__ Xfw, const float* __restrict__ Xbw,
    const float* __restrict__ Wfw, const float* __restrict__ Wbw,
    float* __restrict__ hbuf,           // [2 dir][2 parity][16][512]
    float* __restrict__ Hcat,           // [1536][1024]
    unsigned int* __restrict__ cnt)     // [2*32], zeroed
{
  __shared__ unsigned int W_s32[512*16];   // 32 KB: [k][cp] two bf16 packed
  __shared__ float h_s[16][512];           // 32 KB
  const int bid = blockIdx.x;
  const int dir = bid >> 6;
  const int slice = bid & 63;
  const int u0 = slice * 8;
  const int t = threadIdx.x;
  const float* X = dir ? Xbw : Xfw;
  const float* W = (dir ? Wbw : Wfw) + (long long)E_*2048;
  // stage W slice: cols c = g*8+ul -> W[.][g*512 + u0 + ul], packed in pairs
  for (int rep = 0; rep < 32; rep++){
    int pidx = rep*256 + t;            // 0..8191
    int k = pidx >> 4, cp = pidx & 15;
    int c0 = cp*2, c1 = cp*2 + 1;
    float w0 = W[(long long)k*2048 + (c0>>3)*512 + u0 + (c0&7)];
    float w1 = W[(long long)k*2048 + (c1>>3)*512 + u0 + (c1&7)];
    W_s32[k*16 + cp] = (unsigned int)f2bf(w0) | ((unsigned int)f2bf(w1) << 16);
  }
  const int b = t >> 4, cp = t & 15;
  const int c0 = cp*2, c1 = cp*2 + 1;
  const int g0 = c0 >> 3, ul0 = c0 & 7;
  const int g1 = c1 >> 3, ul1 = c1 & 7;
  float creg = 0.f;                       // t<128: c-state of (b=t>>3, u=u0+(t&7))
  unsigned int* mycnt = cnt + dir*32;
  float* hb = hbuf + (long long)dir*2*B_*H_;
  __syncthreads();
  for (int step = 0; step < J_; step++){
    const int cur = step & 1, nxt = cur ^ 1;
    {
      const float4* src = (const float4*)(hb + (long long)cur*B_*H_);
      float4* dst = (float4*)&h_s[0][0];
      #pragma unroll
      for (int r = 0; r < 8; r++) dst[r*256 + t] = src[r*256 + t];
    }
    __syncthreads();
    const int t_eff = dir ? (J_-1-step) : step;
    const long long row = (long long)b*J_ + t_eff;
    float z0 = X[row*2048 + g0*512 + u0 + ul0];
    float z1 = X[row*2048 + g1*512 + u0 + ul1];
    for (int k = 0; k < 512; k += 4){
      float4 hv = *(const float4*)&h_s[b][k];
      unsigned int wp0 = W_s32[(k+0)*16 + cp];
      unsigned int wp1 = W_s32[(k+1)*16 + cp];
      unsigned int wp2 = W_s32[(k+2)*16 + cp];
      unsigned int wp3 = W_s32[(k+3)*16 + cp];
      z0 += hv.x*__uint_as_float(wp0<<16); z1 += hv.x*__uint_as_float(wp0&0xffff0000u);
      z0 += hv.y*__uint_as_float(wp1<<16); z1 += hv.y*__uint_as_float(wp1&0xffff0000u);
      z0 += hv.z*__uint_as_float(wp2<<16); z1 += hv.z*__uint_as_float(wp2&0xffff0000u);
      z0 += hv.w*__uint_as_float(wp3<<16); z1 += hv.w*__uint_as_float(wp3&0xffff0000u);
    }
    __syncthreads();                     // all h_s reads done
    float* zb = (float*)&h_s[0][0];      // alias first 512 floats as z buffer
    zb[b*32 + c0] = z0;
    zb[b*32 + c1] = z1;
    __syncthreads();
    if (t < 128){
      int bb = t >> 3, uu = t & 7;
      float zi = zb[bb*32 +  0 + uu];
      float zg = zb[bb*32 +  8 + uu];
      float zf = zb[bb*32 + 16 + uu];
      float zo = zb[bb*32 + 24 + uu];
      float cc = creg;
      cc = sigf(zf + 1.f)*cc + sigf(zi)*tanhf(zg);
      float hh = sigf(zo)*tanhf(cc);
      creg = cc;
      hb[(long long)nxt*B_*H_ + bb*H_ + u0 + uu] = hh;
      Hcat[((long long)bb*J_ + t_eff)*(2*H_) + dir*H_ + u0 + uu] = hh;
    }
    __threadfence();
    __syncthreads();
    if (t == 0){
      __hip_atomic_fetch_add(mycnt, 1u, __ATOMIC_RELEASE, __HIP_MEMORY_SCOPE_AGENT);
      unsigned int target = 64u*(unsigned)(step+1);
      while (__hip_atomic_load(mycnt, __ATOMIC_ACQUIRE, __HIP_MEMORY_SCOPE_AGENT) < target)
        __builtin_amdgcn_s_sleep(1);
      __threadfence();
    }
    __syncthreads();
  }
}

// Wv fp32 [512][32000] -> WvT bf16 [32000][512]
__global__ void k_wvt(const float* __restrict__ Wv, unsigned short* __restrict__ WvT){
  __shared__ float tile[64][65];
  int n0 = blockIdx.x*64, k0 = blockIdx.y*64;
  int t = threadIdx.x;
  for (int rep = 0; rep < 16; rep++){
    int idx = rep*256 + t;
    int kk = idx >> 6, nn = idx & 63;
    tile[kk][nn] = Wv[(long long)(k0+kk)*VS_ + n0 + nn];
  }
  __syncthreads();
  for (int rep = 0; rep < 16; rep++){
    int idx = rep*256 + t;
    int nn = idx >> 6, kk = idx & 63;
    WvT[(long long)(n0+nn)*H_ + k0 + kk] = f2bf(tile[kk][nn]);
  }
}

// bf16 MFMA GEMM: rowsum[m] += sum_n exp( A[1536,512] @ WvT[n][512]^T + bv[n] )
__global__ __launch_bounds__(256, 2) void k_vgemm(
    const unsigned short* __restrict__ Ah,    // [1536][512]
    const unsigned short* __restrict__ Bh,    // [32000][512]
    const float* __restrict__ bv,
    float* __restrict__ rowsum)
{
  __shared__ unsigned short As[128*32];
  __shared__ unsigned short Bs[128*32];
  // bijective XCD swizzle: 3000 = 8 * 375
  int braw = blockIdx.x;
  int wg = (braw & 7)*375 + (braw >> 3);
  int mt = wg % 12, nt = wg / 12;
  const int m0 = mt*128, n0 = nt*128;
  const int t = threadIdx.x;
  const int lane = t & 63, w = t >> 6;
  const int wm = (w >> 1)*64, wn = (w & 1)*64;
  f32x4 acc[4][4] = {};
  for (int k0 = 0; k0 < 512; k0 += 32){
    #pragma unroll
    for (int p = 0; p < 2; p++){
      int rowA = p*64 + (t >> 2);
      int kc = (t & 3) ^ ((rowA >> 1) & 3);
      const unsigned short* ga = Ah + (long long)(m0 + rowA)*512 + k0 + kc*8;
      const unsigned short* gb = Bh + (long long)(n0 + rowA)*512 + k0 + kc*8;
      unsigned short* la = As + p*2048 + w*512;   // wave-uniform base (bytes: p*4096+w*1024)
      unsigned short* lb = Bs + p*2048 + w*512;
      ASYNC16(ga, la);
      ASYNC16(gb, lb);
    }
    __syncthreads();
    short8 af[4], bf[4];
    const int rr = lane & 15, kch = lane >> 4;
    #pragma unroll
    for (int mi = 0; mi < 4; mi++){
      int rowA = wm + mi*16 + rr;
      int slot = kch ^ ((rowA >> 1) & 3);
      af[mi] = *(const short8*)&As[rowA*32 + slot*8];
    }
    #pragma unroll
    for (int ni = 0; ni < 4; ni++){
      int rowB = wn + ni*16 + rr;
      int slot = kch ^ ((rowB >> 1) & 3);
      bf[ni] = *(const short8*)&Bs[rowB*32 + slot*8];
    }
    #pragma unroll
    for (int mi = 0; mi < 4; mi++)
      #pragma unroll
      for (int ni = 0; ni < 4; ni++)
        acc[mi][ni] = __builtin_amdgcn_mfma_f32_16x16x32_bf16(af[mi], bf[ni], acc[mi][ni], 0, 0, 0);
    __syncthreads();
  }
  // epilogue: exp + row reduction
  #pragma unroll
  for (int mi = 0; mi < 4; mi++){
    #pragma unroll
    for (int r = 0; r < 4; r++){
      int row = m0 + wm + mi*16 + ((lane >> 4) << 2) + r;
      float s = 0.f;
      #pragma unroll
      for (int ni = 0; ni < 4; ni++){
        int col = n0 + wn + ni*16 + (lane & 15);
        s += __expf(acc[mi][ni][r] + bv[col]);
      }
      s += __shfl_xor(s, 1);
      s += __shfl_xor(s, 2);
      s += __shfl_xor(s, 4);
      s += __shfl_xor(s, 8);
      if ((lane & 15) == 0) atomicAdd(&rowsum[row], s);
    }
  }
}

__global__ void k_tn(const int* __restrict__ tnull, const float* __restrict__ emb,
                     const float* __restrict__ W1, const float* __restrict__ b1,
                     float* __restrict__ tn){
  __shared__ float en[E_];
  int t = tnull[0];
  en[threadIdx.x] = emb[(long long)t*E_ + threadIdx.x];
  __syncthreads();
  int u = blockIdx.x*256 + threadIdx.x;
  float s = b1[u];
  for (int e = 0; e < E_; e++) s += en[e]*W1[(long long)e*H_ + u];
  tn[u] = tanhf(s);
}

__global__ void k_p0(const float* __restrict__ tn, const float* __restrict__ Wp,
                     const float* __restrict__ bp, float* __restrict__ p0){
  __shared__ float red[256];
  int tid = threadIdx.x;
  red[tid] = tn[tid]*Wp[tid] + tn[tid+256]*Wp[tid+256];
  __syncthreads();
  for (int w = 128; w > 0; w >>= 1){
    if (tid < w) red[tid] += red[tid+w];
    __syncthreads();
  }
  if (tid == 0) p0[0] = sigf(red[0] + bp[0])*0.3f;
}

__global__ void k_nullrow(const float* __restrict__ tn, const float* __restrict__ Wv,
                          const float* __restrict__ bv, float* __restrict__ lognull,
                          float* __restrict__ nullsum){
  __shared__ float tns[H_];
  __shared__ float red[256];
  int tid = threadIdx.x;
  tns[tid] = tn[tid]; tns[tid+256] = tn[tid+256];
  __syncthreads();
  int c = blockIdx.x*256 + tid;
  float s = bv[c];
  for (int k = 0; k < H_; k++) s += tns[k]*Wv[(long long)k*VS_ + c];
  lognull[c] = s;
  red[tid] = __expf(s);
  __syncthreads();
  for (int w = 128; w > 0; w >>= 1){
    if (tid < w) red[tid] += red[tid+w];
    __syncthreads();
  }
  if (tid == 0) atomicAdd(nullsum, red[0]);
}

__global__ void k_gather(const int* __restrict__ sources, const float* __restrict__ Wv,
                         const float* __restrict__ bv, float* __restrict__ WgT,
                         float* __restrict__ bg){
  int bk = blockIdx.x;           // b*H_ + k
  int b = bk >> 9, k = bk & 511;
  int i = threadIdx.x;
  if (i >= I_) return;
  int s = sources[b*I_ + i];
  WgT[((long long)b*H_ + k)*I_ + i] = Wv[(long long)k*VS_ + s];
  if (k == 0) bg[b*I_ + i] = bv[s];
}

__global__ void k_emission(const float* __restrict__ gl, const float* __restrict__ rowsum,
                           const float* __restrict__ lognull, const float* __restrict__ nullsum,
                           const int* __restrict__ sources, float* __restrict__ out_em){
  int bx = blockIdx.x;           // b*192 + jj
  int b = bx / 192, jj = bx % 192;
  int i = threadIdx.x;
  if (i >= I_) return;
  float v;
  if (jj < J_) v = __expf(gl[((long long)b*J_ + jj)*I_ + i]) / rowsum[b*J_ + jj];
  else { int s = sources[b*I_ + i]; v = __expf(lognull[s]) / nullsum[0]; }
  out_em[(long long)bx*I_ + i] = v;
}

__global__ void k_transition(const float* __restrict__ jlog, const float* __restrict__ p0p,
                             float* __restrict__ T, float* __restrict__ TL){
  int bx = blockIdx.x;           // b*J_ + j
  int b = bx / J_, j = bx % J_;
  int tid = threadIdx.x;         // 128
  __shared__ float ex[128];
  __shared__ float red[128];
  float e = 0.f;
  if (tid < 96) e = __expf(jlog[(long long)bx*SJ_ + (96 - j + tid)]);
  ex[tid] = e; red[tid] = e;
  __syncthreads();
  for (int w = 64; w > 0; w >>= 1){
    if (tid < w) red[tid] += red[tid+w];
    __syncthreads();
  }
  float p0 = p0p[0];
  float scale = (1.f - p0) / red[0];
  float lp0 = logf(p0);
  long long r0 = ((long long)b*192 + j)*192;
  long long r1 = ((long long)b*192 + j + 96)*192;
  for (int col = tid; col < 192; col += 128){
    float tv, lv;
    if (col < 96){ tv = ex[col]*scale; lv = logf(tv); }
    else { bool d = (col - 96) == j; tv = d ? p0 : 0.f; lv = d ? lp0 : 0.f; }
    T[r0 + col] = tv; T[r1 + col] = tv;
    TL[r0 + col] = lv; TL[r1 + col] = lv;
  }
}

extern "C" void kernel_launch(void* const* d_in, const int* in_sizes, int n_in,
                              void* d_out, int out_size, void* d_ws, size_t ws_size,
                              hipStream_t stream)
{
  const int* sources = (const int*)d_in[0];
  const int* targets = (const int*)d_in[1];
  const int* tnull   = (const int*)d_in[2];
  const float* emb   = (const float*)d_in[3];
  const float* Wfw   = (const float*)d_in[4];
  const float* bfw   = (const float*)d_in[5];
  const float* Wbw   = (const float*)d_in[6];
  const float* bbw   = (const float*)d_in[7];
  const float* Wl    = (const float*)d_in[8];
  const float* W1    = (const float*)d_in[9];
  const float* b1    = (const float*)d_in[10];
  const float* Wv    = (const float*)d_in[11];
  const float* bv    = (const float*)d_in[12];
  const float* Wj    = (const float*)d_in[13];
  const float* bj    = (const float*)d_in[14];
  const float* Wp    = (const float*)d_in[15];
  const float* bp    = (const float*)d_in[16];
  float* out = (float*)d_out;
  float* ws  = (float*)d_ws;

  long long off = 0;
  float* e_word = ws + off; off += (long long)NROW*E_;
  float* Xfw    = ws + off; off += (long long)NROW*2048;
  float* Xbw    = ws + off; off += (long long)NROW*2048;
  float* Hcat   = ws + off; off += (long long)NROW*1024;
  float* hbuf   = ws + off; off += 2*2*B_*H_;            // [dir][parity][16][512]
  float* ts     = ws + off; off += (long long)NROW*E_;
  float* t1     = ws + off; off += (long long)NROW*H_;
  unsigned short* t1h = (unsigned short*)(ws + off); off += (long long)NROW*H_/2;
  float* tn     = ws + off; off += H_;
  float* rowsum = ws + off; off += NROW;
  float* nullsum= ws + off; off += 1;
  unsigned int* cnt = (unsigned int*)(ws + off); off += 64;
  float* p0     = ws + off; off += 1;
  float* gl     = ws + off; off += (long long)NROW*I_;
  float* WgT    = ws + off; off += (long long)B_*H_*I_;
  float* bg     = ws + off; off += B_*I_;
  float* lognull= ws + off; off += VS_;
  float* jlog   = ws + off; off += (long long)NROW*SJ_;
  unsigned short* WvT = (unsigned short*)(ws + off); off += (long long)VS_*H_/2;

  float* out_em = out;
  float* out_T  = out + (long long)B_*192*96;
  float* out_TL = out_T + (long long)B_*192*192;

  // per-call init: hbuf (recurrent state) and rowsum+nullsum+cnt (contiguous)
  k_zero<<<(2*2*B_*H_+255)/256, 256, 0, stream>>>(hbuf, 2*2*B_*H_);
  k_zero<<<7, 256, 0, stream>>>(rowsum, NROW + 1 + 64);

  k_embed<<<NROW, 256, 0, stream>>>(targets, emb, e_word);

  // Wv -> bf16 transposed (for MFMA GEMM)
  k_wvt<<<dim3(VS_/64, H_/64), 256, 0, stream>>>(Wv, WvT);

  // input projections for both directions: [1536,256] @ [256,2048] + b
  dim3 gx(2048/64, NROW/64);
  k_gemm<0><<<gx, 256, 0, stream>>>(e_word, E_, 0, Wfw, 2048, 0, Xfw, 2048, 0,
                                    NROW, 2048, E_, bfw, 0, nullptr);
  k_gemm<0><<<gx, 256, 0, stream>>>(e_word, E_, 0, Wbw, 2048, 0, Xbw, 2048, 0,
                                    NROW, 2048, E_, bbw, 0, nullptr);

  // persistent bi-LSTM (replaces 96 per-step launches)
  k_lstm_persist<<<128, 256, 0, stream>>>(Xfw, Xbw, Wfw, Wbw, hbuf, Hcat, cnt);

  // ts = Hcat @ W_lstm   [1536,1024]@[1024,256]
  k_gemm<0><<<dim3(E_/64, NROW/64), 256, 0, stream>>>(Hcat, 2*H_, 0, Wl, E_, 0,
                                                      ts, E_, 0, NROW, E_, 2*H_,
                                                      nullptr, 0, nullptr);
  // t1 = tanh(ts @ W1 + b1)   [1536,256]@[256,512]  (+ bf16 copy t1h)
  k_gemm<1><<<dim3(H_/64, NROW/64), 256, 0, stream>>>(ts, E_, 0, W1, H_, 0,
                                                      t1, H_, 0, NROW, H_, E_,
                                                      b1, 0, t1h);

  k_tn<<<2, 256, 0, stream>>>(tnull, emb, W1, b1, tn);
  k_p0<<<1, 256, 0, stream>>>(tn, Wp, bp, p0);
  k_nullrow<<<VS_/256, 256, 0, stream>>>(tn, Wv, bv, lognull, nullsum);
  k_gather<<<B_*H_, 128, 0, stream>>>(sources, Wv, bv, WgT, bg);

  // rowsum[m] = sum_n exp(logits) via bf16 MFMA GEMM
  k_vgemm<<<3000, 256, 0, stream>>>(t1h, WvT, bv, rowsum);

  // gathered logits: per-batch [96,512]@[512,96] + gathered bias (fp32)
  k_gemm<0><<<dim3(2, 2, B_), 256, 0, stream>>>(t1, H_, (long long)J_*H_,
                                                WgT, I_, (long long)H_*I_,
                                                gl, I_, (long long)J_*I_,
                                                J_, I_, H_, bg, I_, nullptr);
  // jump logits: [1536,512]@[512,193] + bj
  k_gemm<0><<<dim3(4, NROW/64), 256, 0, stream>>>(t1, H_, 0, Wj, SJ_, 0,
                                                  jlog, SJ_, 0, NROW, SJ_, H_,
                                                  bj, 0, nullptr);

  k_emission<<<B_*192, 128, 0, stream>>>(gl, rowsum, lognull, nullsum, sources, out_em);
  k_transition<<<NROW, 128, 0, stream>>>(jlog, p0, out_T, out_TL);
}

// Round 3
// 1056.111 us; speedup vs baseline: 5.5096x; 2.6927x over previous
//
#include <hip/hip_runtime.h>
#include <math.h>

#define B_ 16
#define J_ 96
#define I_ 96
#define E_ 256
#define H_ 512
#define VS_ 32000
#define SJ_ 193
#define NROW (B_*J_)   // 1536

typedef __attribute__((ext_vector_type(8))) short short8;
typedef __attribute__((ext_vector_type(4))) float f32x4;

__device__ __forceinline__ float sigf(float x){ return 1.f/(1.f+__expf(-x)); }

__device__ __forceinline__ unsigned short f2bf(float x){
  unsigned int u = __float_as_uint(x);
  unsigned int r = (u + 0x7FFFu + ((u>>16)&1u)) >> 16;
  return (unsigned short)r;
}

#define ASYNC16(gp, lp) __builtin_amdgcn_global_load_lds( \
    (const __attribute__((address_space(1))) unsigned int*)(gp), \
    (__attribute__((address_space(3))) unsigned int*)(lp), 16, 0, 0)

__global__ void k_zero(float* p, int n){
  int i = blockIdx.x*blockDim.x + threadIdx.x;
  if (i < n) p[i] = 0.f;
}

__global__ void k_embed(const int* __restrict__ targets, const float* __restrict__ emb,
                        float* __restrict__ e_word){
  int row = blockIdx.x;
  int t = targets[row];
  e_word[(long long)row*E_ + threadIdx.x] = emb[(long long)t*E_ + threadIdx.x];
}

// Generic 64x64 tiled fp32 GEMM. EPI: 0 = C=A@B+bias, 1 = tanh(A@B+bias) (+bf16 copy)
template<int EPI>
__global__ void k_gemm(const float* __restrict__ A, int lda, long long sA,
                       const float* __restrict__ B, int ldb, long long sB,
                       float* __restrict__ C, int ldc, long long sC,
                       int M, int N, int K,
                       const float* __restrict__ bias, long long sBias,
                       unsigned short* __restrict__ Ch)
{
  const int bz = blockIdx.z;
  A += (long long)bz*sA; B += (long long)bz*sB;
  if (C) C += (long long)bz*sC;
  if (bias) bias += (long long)bz*sBias;
  const int m0 = blockIdx.y*64, n0 = blockIdx.x*64;
  __shared__ float As[16][68];
  __shared__ float Bs[16][68];
  const int tid = threadIdx.x;         // 256
  const int tx = tid & 15, ty = tid >> 4;
  float acc[4][4] = {};
  for (int k0 = 0; k0 < K; k0 += 16){
    {
      const int kk = tid & 15, r0 = tid >> 4;
      #pragma unroll
      for (int i = 0; i < 4; i++){
        int rr = r0 + i*16, m = m0 + rr;
        As[kk][rr] = (m < M) ? A[(long long)m*lda + k0 + kk] : 0.f;
      }
    }
    {
      const int c = tid & 63, k4 = tid >> 6;
      #pragma unroll
      for (int i = 0; i < 4; i++){
        int kk = k4 + i*4, n = n0 + c;
        Bs[kk][c] = (n < N) ? B[(long long)(k0+kk)*ldb + n] : 0.f;
      }
    }
    __syncthreads();
    #pragma unroll
    for (int kk = 0; kk < 16; kk++){
      float a[4], b[4];
      #pragma unroll
      for (int i = 0; i < 4; i++) a[i] = As[kk][ty*4 + i];
      #pragma unroll
      for (int j = 0; j < 4; j++) b[j] = Bs[kk][tx*4 + j];
      #pragma unroll
      for (int i = 0; i < 4; i++)
        #pragma unroll
        for (int j = 0; j < 4; j++)
          acc[i][j] += a[i]*b[j];
    }
    __syncthreads();
  }
  #pragma unroll
  for (int i = 0; i < 4; i++){
    int m = m0 + ty*4 + i;
    if (m >= M) continue;
    #pragma unroll
    for (int j = 0; j < 4; j++){
      int n = n0 + tx*4 + j;
      if (n >= N) continue;
      float v = acc[i][j] + (bias ? bias[n] : 0.f);
      if (EPI == 1) v = tanhf(v);
      C[(long long)m*ldc + n] = v;
      if (EPI == 1 && Ch) Ch[(long long)m*ldc + n] = f2bf(v);
    }
  }
}

// ---------------------------------------------------------------------------
// Persistent bi-LSTM v2: fence-free. 128 blocks (64/dir), each owns 8 hidden
// units (32 gate cols). W slice resident in LDS (bf16, [col][k], XOR-swizzled).
// Per step: z[16,32] = h[16,512] @ W  via MFMA (A-frags loaded directly from a
// cache-bypassing global exchange buffer), elementwise gate update, publish
// h-slice + flag through relaxed agent-scope atomics (no fences, no wbl2).
// hex32: [2 dir][2 parity][16][256] u32 (2 bf16 each). flags: [2 dir][64].
// ---------------------------------------------------------------------------
__global__ __launch_bounds__(512, 1) void k_lstm2(
    const float* __restrict__ Xfw, const float* __restrict__ Xbw,
    const float* __restrict__ Wfw, const float* __restrict__ Wbw,
    unsigned int* __restrict__ hex32,
    unsigned int* __restrict__ flags,
    float* __restrict__ Hcat)
{
  __shared__ unsigned short W_s[32][512];   // 32 KB
  __shared__ float z_s[4][16][36];          // 9 KB (4 K-quarter partials)
  const int bid = blockIdx.x;               // 0..127
  const int dir = bid >> 6;
  const int slice = bid & 63;
  const int u0 = slice * 8;
  const int t = threadIdx.x;                // 0..511
  const int lane = t & 63;
  const int wv = t >> 6;
  const int q = wv >> 1;                    // K-quarter (128 k)
  const int nt = wv & 1;                    // n-tile (16 cols)
  const float* X = dir ? Xbw : Xfw;
  const float* Wg = (dir ? Wbw : Wfw) + (long long)E_*2048;
  unsigned int* hexd = hex32 + dir*2*16*256;
  unsigned int* flg  = flags + dir*64;

  // ---- stage W slice -> LDS bf16 [col][k], 16B-block XOR swizzle ----
  for (int rep = 0; rep < 4; rep++){
    int id = rep*512 + t;                   // 0..2047
    int k = id >> 2, g = id & 3;
    const float* src = Wg + (long long)k*2048 + g*512 + u0;
    float4 w0 = *(const float4*)src;
    float4 w1 = *(const float4*)(src + 4);
    float wv8[8] = {w0.x,w0.y,w0.z,w0.w,w1.x,w1.y,w1.z,w1.w};
    #pragma unroll
    for (int uu = 0; uu < 8; uu++){
      int c = g*8 + uu;
      int byte = (c << 10) + (k << 1);
      byte ^= ((c & 7) << 4);
      *(unsigned short*)((char*)(&W_s[0][0]) + byte) = f2bf(wv8[uu]);
    }
  }

  float creg = 0.f;                         // t<128: c-state of (b=t>>3, u=u0+(t&7))
  const int eb = t >> 3, eu = t & 7;
  const int m = lane & 15, hi = lane >> 4;

  __syncthreads();

  for (int step = 0; step < J_; step++){
    const int cur = step & 1, nxt = cur ^ 1;
    if (step > 0){
      for (;;){
        unsigned int v = __hip_atomic_load(&flg[lane], __ATOMIC_RELAXED,
                                           __HIP_MEMORY_SCOPE_AGENT);
        if (__all((int)(v >= (unsigned)step))) break;
        __builtin_amdgcn_s_sleep(2);
      }
      __builtin_amdgcn_sched_barrier(0);
    }
    const int t_eff = dir ? (J_-1-step) : step;
    // early X loads (waves 0-1 only; X already includes bias)
    float xg[4];
    if (t < 128){
      const float* xr = X + ((long long)eb*J_ + t_eff)*2048 + u0 + eu;
      #pragma unroll
      for (int g = 0; g < 4; g++) xg[g] = xr[g*512];
    }
    // MFMA: partial z over K-quarter q, n-tile nt
    f32x4 acc = {0.f,0.f,0.f,0.f};
    const unsigned long long* hp = (const unsigned long long*)(hexd + cur*16*256);
    #pragma unroll
    for (int ck = 0; ck < 4; ck++){
      int kc = q*4 + ck;
      int k0 = kc*32 + hi*8;
      unsigned long long a0 = __hip_atomic_load(hp + m*128 + (k0 >> 2),
                                                __ATOMIC_RELAXED, __HIP_MEMORY_SCOPE_AGENT);
      unsigned long long a1 = __hip_atomic_load(hp + m*128 + (k0 >> 2) + 1,
                                                __ATOMIC_RELAXED, __HIP_MEMORY_SCOPE_AGENT);
      union { unsigned long long qq[2]; short8 v; } ua;
      ua.qq[0] = a0; ua.qq[1] = a1;
      int col = nt*16 + m;
      int byte = (col << 10) + ((kc*32 + hi*8) << 1);
      byte ^= ((col & 7) << 4);
      short8 bf = *(const short8*)((const char*)(&W_s[0][0]) + byte);
      acc = __builtin_amdgcn_mfma_f32_16x16x32_bf16(ua.v, bf, acc, 0, 0, 0);
    }
    #pragma unroll
    for (int r = 0; r < 4; r++)
      z_s[q][hi*4 + r][nt*16 + m] = acc[r];
    __syncthreads();
    if (t < 128){
      float zg4[4];
      #pragma unroll
      for (int g = 0; g < 4; g++){
        float s = xg[g];
        #pragma unroll
        for (int qq = 0; qq < 4; qq++) s += z_s[qq][eb][g*8 + eu];
        zg4[g] = s;
      }
      float cc = creg;
      cc = sigf(zg4[2] + 1.f)*cc + sigf(zg4[0])*tanhf(zg4[1]);
      float hh = sigf(zg4[3])*tanhf(cc);
      creg = cc;
      Hcat[((long long)eb*J_ + t_eff)*1024 + dir*512 + u0 + eu] = hh;
      unsigned int hb = (unsigned int)f2bf(hh);
      unsigned int nb = (unsigned int)__shfl_xor((int)hb, 1);
      if (!(eu & 1))
        __hip_atomic_store(&hexd[(nxt*16 + eb)*256 + ((u0 + eu) >> 1)],
                           (hb & 0xffffu) | (nb << 16),
                           __ATOMIC_RELAXED, __HIP_MEMORY_SCOPE_AGENT);
    }
    __syncthreads();   // drains each wave's vmcnt -> all h stores at coherence point
    if (t == 0)
      __hip_atomic_store(&flg[slice], (unsigned int)(step+1),
                         __ATOMIC_RELAXED, __HIP_MEMORY_SCOPE_AGENT);
  }
}

// Wv fp32 [512][32000] -> WvT bf16 [32000][512]
__global__ void k_wvt(const float* __restrict__ Wv, unsigned short* __restrict__ WvT){
  __shared__ float tile[64][65];
  int n0 = blockIdx.x*64, k0 = blockIdx.y*64;
  int t = threadIdx.x;
  for (int rep = 0; rep < 16; rep++){
    int idx = rep*256 + t;
    int kk = idx >> 6, nn = idx & 63;
    tile[kk][nn] = Wv[(long long)(k0+kk)*VS_ + n0 + nn];
  }
  __syncthreads();
  for (int rep = 0; rep < 16; rep++){
    int idx = rep*256 + t;
    int nn = idx >> 6, kk = idx & 63;
    WvT[(long long)(n0+nn)*H_ + k0 + kk] = f2bf(tile[kk][nn]);
  }
}

// bf16 MFMA GEMM: rowsum[m] += sum_n exp( A[1536,512] @ WvT[n][512]^T + bv[n] )
__global__ __launch_bounds__(256, 2) void k_vgemm(
    const unsigned short* __restrict__ Ah,    // [1536][512]
    const unsigned short* __restrict__ Bh,    // [32000][512]
    const float* __restrict__ bv,
    float* __restrict__ rowsum)
{
  __shared__ unsigned short As[128*32];
  __shared__ unsigned short Bs[128*32];
  // bijective XCD swizzle: 3000 = 8 * 375
  int braw = blockIdx.x;
  int wg = (braw & 7)*375 + (braw >> 3);
  int mt = wg % 12, nt = wg / 12;
  const int m0 = mt*128, n0 = nt*128;
  const int t = threadIdx.x;
  const int lane = t & 63, w = t >> 6;
  const int wm = (w >> 1)*64, wn = (w & 1)*64;
  f32x4 acc[4][4] = {};
  for (int k0 = 0; k0 < 512; k0 += 32){
    #pragma unroll
    for (int p = 0; p < 2; p++){
      int rowA = p*64 + (t >> 2);
      int kc = (t & 3) ^ ((rowA >> 1) & 3);
      const unsigned short* ga = Ah + (long long)(m0 + rowA)*512 + k0 + kc*8;
      const unsigned short* gb = Bh + (long long)(n0 + rowA)*512 + k0 + kc*8;
      unsigned short* la = As + p*2048 + w*512;
      unsigned short* lb = Bs + p*2048 + w*512;
      ASYNC16(ga, la);
      ASYNC16(gb, lb);
    }
    __syncthreads();
    short8 af[4], bf[4];
    const int rr = lane & 15, kch = lane >> 4;
    #pragma unroll
    for (int mi = 0; mi < 4; mi++){
      int rowA = wm + mi*16 + rr;
      int slot = kch ^ ((rowA >> 1) & 3);
      af[mi] = *(const short8*)&As[rowA*32 + slot*8];
    }
    #pragma unroll
    for (int ni = 0; ni < 4; ni++){
      int rowB = wn + ni*16 + rr;
      int slot = kch ^ ((rowB >> 1) & 3);
      bf[ni] = *(const short8*)&Bs[rowB*32 + slot*8];
    }
    #pragma unroll
    for (int mi = 0; mi < 4; mi++)
      #pragma unroll
      for (int ni = 0; ni < 4; ni++)
        acc[mi][ni] = __builtin_amdgcn_mfma_f32_16x16x32_bf16(af[mi], bf[ni], acc[mi][ni], 0, 0, 0);
    __syncthreads();
  }
  #pragma unroll
  for (int mi = 0; mi < 4; mi++){
    #pragma unroll
    for (int r = 0; r < 4; r++){
      int row = m0 + wm + mi*16 + ((lane >> 4) << 2) + r;
      float s = 0.f;
      #pragma unroll
      for (int ni = 0; ni < 4; ni++){
        int col = n0 + wn + ni*16 + (lane & 15);
        s += __expf(acc[mi][ni][r] + bv[col]);
      }
      s += __shfl_xor(s, 1);
      s += __shfl_xor(s, 2);
      s += __shfl_xor(s, 4);
      s += __shfl_xor(s, 8);
      if ((lane & 15) == 0) atomicAdd(&rowsum[row], s);
    }
  }
}

__global__ void k_tn(const int* __restrict__ tnull, const float* __restrict__ emb,
                     const float* __restrict__ W1, const float* __restrict__ b1,
                     float* __restrict__ tn){
  __shared__ float en[E_];
  int t = tnull[0];
  en[threadIdx.x] = emb[(long long)t*E_ + threadIdx.x];
  __syncthreads();
  int u = blockIdx.x*256 + threadIdx.x;
  float s = b1[u];
  for (int e = 0; e < E_; e++) s += en[e]*W1[(long long)e*H_ + u];
  tn[u] = tanhf(s);
}

__global__ void k_p0(const float* __restrict__ tn, const float* __restrict__ Wp,
                     const float* __restrict__ bp, float* __restrict__ p0){
  __shared__ float red[256];
  int tid = threadIdx.x;
  red[tid] = tn[tid]*Wp[tid] + tn[tid+256]*Wp[tid+256];
  __syncthreads();
  for (int w = 128; w > 0; w >>= 1){
    if (tid < w) red[tid] += red[tid+w];
    __syncthreads();
  }
  if (tid == 0) p0[0] = sigf(red[0] + bp[0])*0.3f;
}

__global__ void k_nullrow(const float* __restrict__ tn, const float* __restrict__ Wv,
                          const float* __restrict__ bv, float* __restrict__ lognull,
                          float* __restrict__ nullsum){
  __shared__ float tns[H_];
  __shared__ float red[256];
  int tid = threadIdx.x;
  tns[tid] = tn[tid]; tns[tid+256] = tn[tid+256];
  __syncthreads();
  int c = blockIdx.x*256 + tid;
  float s = bv[c];
  for (int k = 0; k < H_; k++) s += tns[k]*Wv[(long long)k*VS_ + c];
  lognull[c] = s;
  red[tid] = __expf(s);
  __syncthreads();
  for (int w = 128; w > 0; w >>= 1){
    if (tid < w) red[tid] += red[tid+w];
    __syncthreads();
  }
  if (tid == 0) atomicAdd(nullsum, red[0]);
}

__global__ void k_gather(const int* __restrict__ sources, const float* __restrict__ Wv,
                         const float* __restrict__ bv, float* __restrict__ WgT,
                         float* __restrict__ bg){
  int bk = blockIdx.x;           // b*H_ + k
  int b = bk >> 9, k = bk & 511;
  int i = threadIdx.x;
  if (i >= I_) return;
  int s = sources[b*I_ + i];
  WgT[((long long)b*H_ + k)*I_ + i] = Wv[(long long)k*VS_ + s];
  if (k == 0) bg[b*I_ + i] = bv[s];
}

__global__ void k_emission(const float* __restrict__ gl, const float* __restrict__ rowsum,
                           const float* __restrict__ lognull, const float* __restrict__ nullsum,
                           const int* __restrict__ sources, float* __restrict__ out_em){
  int bx = blockIdx.x;           // b*192 + jj
  int b = bx / 192, jj = bx % 192;
  int i = threadIdx.x;
  if (i >= I_) return;
  float v;
  if (jj < J_) v = __expf(gl[((long long)b*J_ + jj)*I_ + i]) / rowsum[b*J_ + jj];
  else { int s = sources[b*I_ + i]; v = __expf(lognull[s]) / nullsum[0]; }
  out_em[(long long)bx*I_ + i] = v;
}

__global__ void k_transition(const float* __restrict__ jlog, const float* __restrict__ p0p,
                             float* __restrict__ T, float* __restrict__ TL){
  int bx = blockIdx.x;           // b*J_ + j
  int b = bx / J_, j = bx % J_;
  int tid = threadIdx.x;         // 128
  __shared__ float ex[128];
  __shared__ float red[128];
  float e = 0.f;
  if (tid < 96) e = __expf(jlog[(long long)bx*SJ_ + (96 - j + tid)]);
  ex[tid] = e; red[tid] = e;
  __syncthreads();
  for (int w = 64; w > 0; w >>= 1){
    if (tid < w) red[tid] += red[tid+w];
    __syncthreads();
  }
  float p0 = p0p[0];
  float scale = (1.f - p0) / red[0];
  float lp0 = logf(p0);
  long long r0 = ((long long)b*192 + j)*192;
  long long r1 = ((long long)b*192 + j + 96)*192;
  for (int col = tid; col < 192; col += 128){
    float tv, lv;
    if (col < 96){ tv = ex[col]*scale; lv = logf(tv); }
    else { bool d = (col - 96) == j; tv = d ? p0 : 0.f; lv = d ? lp0 : 0.f; }
    T[r0 + col] = tv; T[r1 + col] = tv;
    TL[r0 + col] = lv; TL[r1 + col] = lv;
  }
}

extern "C" void kernel_launch(void* const* d_in, const int* in_sizes, int n_in,
                              void* d_out, int out_size, void* d_ws, size_t ws_size,
                              hipStream_t stream)
{
  const int* sources = (const int*)d_in[0];
  const int* targets = (const int*)d_in[1];
  const int* tnull   = (const int*)d_in[2];
  const float* emb   = (const float*)d_in[3];
  const float* Wfw   = (const float*)d_in[4];
  const float* bfw   = (const float*)d_in[5];
  const float* Wbw   = (const float*)d_in[6];
  const float* bbw   = (const float*)d_in[7];
  const float* Wl    = (const float*)d_in[8];
  const float* W1    = (const float*)d_in[9];
  const float* b1    = (const float*)d_in[10];
  const float* Wv    = (const float*)d_in[11];
  const float* bv    = (const float*)d_in[12];
  const float* Wj    = (const float*)d_in[13];
  const float* bj    = (const float*)d_in[14];
  const float* Wp    = (const float*)d_in[15];
  const float* bp    = (const float*)d_in[16];
  float* out = (float*)d_out;
  float* ws  = (float*)d_ws;

  long long off = 0;
  float* e_word = ws + off; off += (long long)NROW*E_;
  float* Xfw    = ws + off; off += (long long)NROW*2048;
  float* Xbw    = ws + off; off += (long long)NROW*2048;
  float* Hcat   = ws + off; off += (long long)NROW*1024;
  unsigned int* hex32 = (unsigned int*)(ws + off); off += 2*2*16*256;  // 16384 words
  unsigned int* flags = (unsigned int*)(ws + off); off += 128;
  float* ts     = ws + off; off += (long long)NROW*E_;
  float* t1     = ws + off; off += (long long)NROW*H_;
  unsigned short* t1h = (unsigned short*)(ws + off); off += (long long)NROW*H_/2;
  float* tn     = ws + off; off += H_;
  float* rowsum = ws + off; off += NROW;
  float* nullsum= ws + off; off += 1;
  float* p0     = ws + off; off += 1;
  float* gl     = ws + off; off += (long long)NROW*I_;
  float* WgT    = ws + off; off += (long long)B_*H_*I_;
  float* bg     = ws + off; off += B_*I_;
  float* lognull= ws + off; off += VS_;
  float* jlog   = ws + off; off += (long long)NROW*SJ_;
  unsigned short* WvT = (unsigned short*)(ws + off); off += (long long)VS_*H_/2;

  float* out_em = out;
  float* out_T  = out + (long long)B_*192*96;
  float* out_TL = out_T + (long long)B_*192*192;

  // per-call init: h-exchange + flags (contiguous), rowsum + nullsum (contiguous)
  k_zero<<<(2*2*16*256 + 128 + 255)/256, 256, 0, stream>>>((float*)hex32, 2*2*16*256 + 128);
  k_zero<<<7, 256, 0, stream>>>(rowsum, NROW + 1);

  k_embed<<<NROW, 256, 0, stream>>>(targets, emb, e_word);

  // Wv -> bf16 transposed (for MFMA GEMM)
  k_wvt<<<dim3(VS_/64, H_/64), 256, 0, stream>>>(Wv, WvT);

  // input projections for both directions: [1536,256] @ [256,2048] + b
  dim3 gx(2048/64, NROW/64);
  k_gemm<0><<<gx, 256, 0, stream>>>(e_word, E_, 0, Wfw, 2048, 0, Xfw, 2048, 0,
                                    NROW, 2048, E_, bfw, 0, nullptr);
  k_gemm<0><<<gx, 256, 0, stream>>>(e_word, E_, 0, Wbw, 2048, 0, Xbw, 2048, 0,
                                    NROW, 2048, E_, bbw, 0, nullptr);

  // persistent fence-free bi-LSTM
  k_lstm2<<<128, 512, 0, stream>>>(Xfw, Xbw, Wfw, Wbw, hex32, flags, Hcat);

  // ts = Hcat @ W_lstm   [1536,1024]@[1024,256]
  k_gemm<0><<<dim3(E_/64, NROW/64), 256, 0, stream>>>(Hcat, 2*H_, 0, Wl, E_, 0,
                                                      ts, E_, 0, NROW, E_, 2*H_,
                                                      nullptr, 0, nullptr);
  // t1 = tanh(ts @ W1 + b1)   [1536,256]@[256,512]  (+ bf16 copy t1h)
  k_gemm<1><<<dim3(H_/64, NROW/64), 256, 0, stream>>>(ts, E_, 0, W1, H_, 0,
                                                      t1, H_, 0, NROW, H_, E_,
                                                      b1, 0, t1h);

  k_tn<<<2, 256, 0, stream>>>(tnull, emb, W1, b1, tn);
  k_p0<<<1, 256, 0, stream>>>(tn, Wp, bp, p0);
  k_nullrow<<<VS_/256, 256, 0, stream>>>(tn, Wv, bv, lognull, nullsum);
  k_gather<<<B_*H_, 128, 0, stream>>>(sources, Wv, bv, WgT, bg);

  // rowsum[m] = sum_n exp(logits) via bf16 MFMA GEMM
  k_vgemm<<<3000, 256, 0, stream>>>(t1h, WvT, bv, rowsum);

  // gathered logits: per-batch [96,512]@[512,96] + gathered bias (fp32)
  k_gemm<0><<<dim3(2, 2, B_), 256, 0, stream>>>(t1, H_, (long long)J_*H_,
                                                WgT, I_, (long long)H_*I_,
                                                gl, I_, (long long)J_*I_,
                                                J_, I_, H_, bg, I_, nullptr);
  // jump logits: [1536,512]@[512,193] + bj
  k_gemm<0><<<dim3(4, NROW/64), 256, 0, stream>>>(t1, H_, 0, Wj, SJ_, 0,
                                                  jlog, SJ_, 0, NROW, SJ_, H_,
                                                  bj, 0, nullptr);

  k_emission<<<B_*192, 128, 0, stream>>>(gl, rowsum, lognull, nullsum, sources, out_em);
  k_transition<<<NROW, 128, 0, stream>>>(jlog, p0, out_T, out_TL);
}

// Round 4
// 900.849 us; speedup vs baseline: 6.4592x; 1.1724x over previous
//
#include <hip/hip_runtime.h>
#include <math.h>

#define B_ 16
#define J_ 96
#define I_ 96
#define E_ 256
#define H_ 512
#define VS_ 32000
#define SJ_ 193
#define NROW (B_*J_)   // 1536

typedef __attribute__((ext_vector_type(8))) short short8;
typedef __attribute__((ext_vector_type(4))) float f32x4;
typedef __attribute__((ext_vector_type(4))) unsigned int u32x4;

__device__ __forceinline__ float sigf(float x){ return 1.f/(1.f+__expf(-x)); }

__device__ __forceinline__ unsigned short f2bf(float x){
  unsigned int u = __float_as_uint(x);
  unsigned int r = (u + 0x7FFFu + ((u>>16)&1u)) >> 16;
  return (unsigned short)r;
}

#define ASYNC16(gp, lp) __builtin_amdgcn_global_load_lds( \
    (const __attribute__((address_space(1))) unsigned int*)(gp), \
    (__attribute__((address_space(3))) unsigned int*)(lp), 16, 0, 0)

__global__ void k_init(unsigned int* __restrict__ hexflags, float* __restrict__ rowsum){
  int i = blockIdx.x*256 + threadIdx.x;
  if (i < 16384 + 128) hexflags[i] = 0u;
  if (i < NROW + 1) rowsum[i] = 0.f;
}

__global__ void k_embed(const int* __restrict__ targets, const float* __restrict__ emb,
                        float* __restrict__ e_word){
  int row = blockIdx.x;
  int t = targets[row];
  e_word[(long long)row*E_ + threadIdx.x] = emb[(long long)t*E_ + threadIdx.x];
}

// Generic 64x64 tiled fp32 GEMM. EPI: 0 = C=A@B+bias, 1 = tanh(A@B+bias) (+bf16 copy)
template<int EPI>
__global__ void k_gemm(const float* __restrict__ A, int lda, long long sA,
                       const float* __restrict__ B, int ldb, long long sB,
                       float* __restrict__ C, int ldc, long long sC,
                       int M, int N, int K,
                       const float* __restrict__ bias, long long sBias,
                       unsigned short* __restrict__ Ch)
{
  const int bz = blockIdx.z;
  A += (long long)bz*sA; B += (long long)bz*sB;
  if (C) C += (long long)bz*sC;
  if (bias) bias += (long long)bz*sBias;
  const int m0 = blockIdx.y*64, n0 = blockIdx.x*64;
  __shared__ float As[16][68];
  __shared__ float Bs[16][68];
  const int tid = threadIdx.x;         // 256
  const int tx = tid & 15, ty = tid >> 4;
  float acc[4][4] = {};
  for (int k0 = 0; k0 < K; k0 += 16){
    {
      const int kk = tid & 15, r0 = tid >> 4;
      #pragma unroll
      for (int i = 0; i < 4; i++){
        int rr = r0 + i*16, m = m0 + rr;
        As[kk][rr] = (m < M) ? A[(long long)m*lda + k0 + kk] : 0.f;
      }
    }
    {
      const int c = tid & 63, k4 = tid >> 6;
      #pragma unroll
      for (int i = 0; i < 4; i++){
        int kk = k4 + i*4, n = n0 + c;
        Bs[kk][c] = (n < N) ? B[(long long)(k0+kk)*ldb + n] : 0.f;
      }
    }
    __syncthreads();
    #pragma unroll
    for (int kk = 0; kk < 16; kk++){
      float a[4], b[4];
      #pragma unroll
      for (int i = 0; i < 4; i++) a[i] = As[kk][ty*4 + i];
      #pragma unroll
      for (int j = 0; j < 4; j++) b[j] = Bs[kk][tx*4 + j];
      #pragma unroll
      for (int i = 0; i < 4; i++)
        #pragma unroll
        for (int j = 0; j < 4; j++)
          acc[i][j] += a[i]*b[j];
    }
    __syncthreads();
  }
  #pragma unroll
  for (int i = 0; i < 4; i++){
    int m = m0 + ty*4 + i;
    if (m >= M) continue;
    #pragma unroll
    for (int j = 0; j < 4; j++){
      int n = n0 + tx*4 + j;
      if (n >= N) continue;
      float v = acc[i][j] + (bias ? bias[n] : 0.f);
      if (EPI == 1) v = tanhf(v);
      C[(long long)m*ldc + n] = v;
      if (EPI == 1 && Ch) Ch[(long long)m*ldc + n] = f2bf(v);
    }
  }
}

// ---------------------------------------------------------------------------
// Persistent bi-LSTM v3: latency-trimmed. 128 blocks x 256 thr (64/dir),
// each owns 8 hidden units (32 gate cols). Wave q = K-quarter q.
// Step loop: X prefetch (pre-poll) -> poll flags -> 4x 16B sc0/sc1 A-loads
// -> 8 MFMAs (B-frags hoisted in registers) -> LDS reduce -> gates ->
// publish h + flag (relaxed agent atomics) -> Hcat store (post-flag).
// hex32: [2 dir][2 parity][16][256] u32 (2 bf16 each). flags: [2 dir][64].
// ---------------------------------------------------------------------------
__global__ __launch_bounds__(256, 2) void k_lstm3(
    const float* __restrict__ Xfw, const float* __restrict__ Xbw,
    const float* __restrict__ Wfw, const float* __restrict__ Wbw,
    unsigned int* __restrict__ hex32,
    unsigned int* __restrict__ flags,
    float* __restrict__ Hcat)
{
  __shared__ unsigned short W_s[32*512];    // 32 KB, [col][k] bf16, XOR-swizzled
  __shared__ float z_s[4][16][36];          // per-quarter partials
  const int bid = blockIdx.x;               // 0..127
  const int dir = bid >> 6;
  const int slice = bid & 63;
  const int u0 = slice * 8;
  const int t = threadIdx.x;                // 0..255
  const int lane = t & 63;
  const int q = t >> 6;                     // wave = K-quarter
  const int m = lane & 15, hi = lane >> 4;
  const float* X = dir ? Xbw : Xfw;
  const float* Wg = (dir ? Wbw : Wfw) + (long long)E_*2048;
  unsigned int* hexd = hex32 + dir*2*4096;
  unsigned int* flg  = flags + dir*64;

  // ---- stage W slice -> LDS bf16 [col][k], 16B-block XOR swizzle ----
  for (int rep = 0; rep < 8; rep++){
    int id = rep*256 + t;                   // 0..2047
    int k = id >> 2, g = id & 3;
    const float* src = Wg + (long long)k*2048 + g*512 + u0;
    float4 w0 = *(const float4*)src;
    float4 w1 = *(const float4*)(src + 4);
    float wv8[8] = {w0.x,w0.y,w0.z,w0.w,w1.x,w1.y,w1.z,w1.w};
    #pragma unroll
    for (int uu = 0; uu < 8; uu++){
      int c = g*8 + uu;
      int byte = (c << 10) + (k << 1);
      byte ^= ((c & 7) << 4);
      *(unsigned short*)((char*)W_s + byte) = f2bf(wv8[uu]);
    }
  }
  __syncthreads();

  // ---- hoist B-fragments (loop-invariant across all 96 steps) ----
  short8 bfr[2][4];
  #pragma unroll
  for (int nt = 0; nt < 2; nt++)
    #pragma unroll
    for (int ck = 0; ck < 4; ck++){
      int col = nt*16 + m;
      int kc = q*4 + ck;
      int byte = (col << 10) + kc*64 + hi*16;
      byte ^= ((col & 7) << 4);
      bfr[nt][ck] = *(const short8*)((const char*)W_s + byte);
    }

  float creg = 0.f;                         // t<128: c-state of (b=t>>3, u=u0+(t&7))
  const int eb = t >> 3, eu = t & 7;

  for (int step = 0; step < J_; step++){
    const int cur = step & 1, nxt = cur ^ 1;
    const int t_eff = dir ? (J_-1-step) : step;
    // X prefetch BEFORE poll (latency hides under the spin)
    float xg0=0.f, xg1=0.f, xg2=0.f, xg3=0.f;
    if (t < 128){
      const float* xr = X + ((long long)eb*J_ + t_eff)*2048 + u0 + eu;
      xg0 = xr[0]; xg1 = xr[512]; xg2 = xr[1024]; xg3 = xr[1536];
    }
    if (step > 0){
      for (;;){
        unsigned int v = __hip_atomic_load(&flg[lane], __ATOMIC_RELAXED,
                                           __HIP_MEMORY_SCOPE_AGENT);
        if (__all((int)(v >= (unsigned)step))) break;
        __builtin_amdgcn_s_sleep(1);
      }
    }
    __builtin_amdgcn_sched_barrier(0);
    // A-fragment loads: 16B each, cache-bypassing (visible at coherence point)
    const char* hbp = (const char*)(hexd + cur*4096) + m*1024 + q*256 + hi*16;
    union { u32x4 u; short8 s; } a0, a1, a2, a3;
    asm volatile("global_load_dwordx4 %0, %1, off sc0 sc1" : "=v"(a0.u) : "v"(hbp));
    asm volatile("global_load_dwordx4 %0, %1, off sc0 sc1" : "=v"(a1.u) : "v"(hbp+64));
    asm volatile("global_load_dwordx4 %0, %1, off sc0 sc1" : "=v"(a2.u) : "v"(hbp+128));
    asm volatile("global_load_dwordx4 %0, %1, off sc0 sc1" : "=v"(a3.u) : "v"(hbp+192));
    asm volatile("s_waitcnt vmcnt(0)" ::: "memory");
    __builtin_amdgcn_sched_barrier(0);
    f32x4 acc0 = {0.f,0.f,0.f,0.f}, acc1 = {0.f,0.f,0.f,0.f};
    acc0 = __builtin_amdgcn_mfma_f32_16x16x32_bf16(a0.s, bfr[0][0], acc0, 0,0,0);
    acc1 = __builtin_amdgcn_mfma_f32_16x16x32_bf16(a0.s, bfr[1][0], acc1, 0,0,0);
    acc0 = __builtin_amdgcn_mfma_f32_16x16x32_bf16(a1.s, bfr[0][1], acc0, 0,0,0);
    acc1 = __builtin_amdgcn_mfma_f32_16x16x32_bf16(a1.s, bfr[1][1], acc1, 0,0,0);
    acc0 = __builtin_amdgcn_mfma_f32_16x16x32_bf16(a2.s, bfr[0][2], acc0, 0,0,0);
    acc1 = __builtin_amdgcn_mfma_f32_16x16x32_bf16(a2.s, bfr[1][2], acc1, 0,0,0);
    acc0 = __builtin_amdgcn_mfma_f32_16x16x32_bf16(a3.s, bfr[0][3], acc0, 0,0,0);
    acc1 = __builtin_amdgcn_mfma_f32_16x16x32_bf16(a3.s, bfr[1][3], acc1, 0,0,0);
    #pragma unroll
    for (int r = 0; r < 4; r++){
      z_s[q][hi*4 + r][m]      = acc0[r];
      z_s[q][hi*4 + r][16 + m] = acc1[r];
    }
    __syncthreads();
    float hh = 0.f;
    if (t < 128){
      float z0 = xg0, z1 = xg1, z2 = xg2, z3 = xg3;
      #pragma unroll
      for (int qq = 0; qq < 4; qq++){
        z0 += z_s[qq][eb][eu];
        z1 += z_s[qq][eb][8 + eu];
        z2 += z_s[qq][eb][16 + eu];
        z3 += z_s[qq][eb][24 + eu];
      }
      float cc = creg;
      cc = sigf(z2 + 1.f)*cc + sigf(z0)*tanhf(z1);
      hh = sigf(z3)*tanhf(cc);
      creg = cc;
      unsigned int hb16 = (unsigned int)f2bf(hh);
      unsigned int nb = (unsigned int)__shfl_xor((int)hb16, 1);
      if (!(eu & 1))
        __hip_atomic_store(&hexd[(nxt*16 + eb)*256 + ((u0 + eu) >> 1)],
                           (hb16 & 0xffffu) | (nb << 16),
                           __ATOMIC_RELAXED, __HIP_MEMORY_SCOPE_AGENT);
    }
    __syncthreads();   // each wave drains its vmcnt -> h stores at coherence point
    if (t == 0)
      __hip_atomic_store(&flg[slice], (unsigned int)(step+1),
                         __ATOMIC_RELAXED, __HIP_MEMORY_SCOPE_AGENT);
    if (t < 128)
      Hcat[((long long)eb*J_ + t_eff)*1024 + dir*512 + u0 + eu] = hh;
  }
}

// Wv fp32 [512][32000] -> WvT bf16 [32000][512]
__global__ void k_wvt(const float* __restrict__ Wv, unsigned short* __restrict__ WvT){
  __shared__ float tile[64][65];
  int n0 = blockIdx.x*64, k0 = blockIdx.y*64;
  int t = threadIdx.x;
  for (int rep = 0; rep < 16; rep++){
    int idx = rep*256 + t;
    int kk = idx >> 6, nn = idx & 63;
    tile[kk][nn] = Wv[(long long)(k0+kk)*VS_ + n0 + nn];
  }
  __syncthreads();
  for (int rep = 0; rep < 16; rep++){
    int idx = rep*256 + t;
    int nn = idx >> 6, kk = idx & 63;
    WvT[(long long)(n0+nn)*H_ + k0 + kk] = f2bf(tile[kk][nn]);
  }
}

// bf16 MFMA GEMM: rowsum[m] += sum_n exp( A[1536,512] @ WvT[n][512]^T + bv[n] )
__global__ __launch_bounds__(256, 2) void k_vgemm(
    const unsigned short* __restrict__ Ah,    // [1536][512]
    const unsigned short* __restrict__ Bh,    // [32000][512]
    const float* __restrict__ bv,
    float* __restrict__ rowsum)
{
  __shared__ unsigned short As[128*32];
  __shared__ unsigned short Bs[128*32];
  // bijective XCD swizzle: 3000 = 8 * 375
  int braw = blockIdx.x;
  int wg = (braw & 7)*375 + (braw >> 3);
  int mt = wg % 12, nt = wg / 12;
  const int m0 = mt*128, n0 = nt*128;
  const int t = threadIdx.x;
  const int lane = t & 63, w = t >> 6;
  const int wm = (w >> 1)*64, wn = (w & 1)*64;
  f32x4 acc[4][4] = {};
  for (int k0 = 0; k0 < 512; k0 += 32){
    #pragma unroll
    for (int p = 0; p < 2; p++){
      int rowA = p*64 + (t >> 2);
      int kc = (t & 3) ^ ((rowA >> 1) & 3);
      const unsigned short* ga = Ah + (long long)(m0 + rowA)*512 + k0 + kc*8;
      const unsigned short* gb = Bh + (long long)(n0 + rowA)*512 + k0 + kc*8;
      unsigned short* la = As + p*2048 + w*512;
      unsigned short* lb = Bs + p*2048 + w*512;
      ASYNC16(ga, la);
      ASYNC16(gb, lb);
    }
    __syncthreads();
    short8 af[4], bf[4];
    const int rr = lane & 15, kch = lane >> 4;
    #pragma unroll
    for (int mi = 0; mi < 4; mi++){
      int rowA = wm + mi*16 + rr;
      int slot = kch ^ ((rowA >> 1) & 3);
      af[mi] = *(const short8*)&As[rowA*32 + slot*8];
    }
    #pragma unroll
    for (int ni = 0; ni < 4; ni++){
      int rowB = wn + ni*16 + rr;
      int slot = kch ^ ((rowB >> 1) & 3);
      bf[ni] = *(const short8*)&Bs[rowB*32 + slot*8];
    }
    #pragma unroll
    for (int mi = 0; mi < 4; mi++)
      #pragma unroll
      for (int ni = 0; ni < 4; ni++)
        acc[mi][ni] = __builtin_amdgcn_mfma_f32_16x16x32_bf16(af[mi], bf[ni], acc[mi][ni], 0, 0, 0);
    __syncthreads();
  }
  #pragma unroll
  for (int mi = 0; mi < 4; mi++){
    #pragma unroll
    for (int r = 0; r < 4; r++){
      int row = m0 + wm + mi*16 + ((lane >> 4) << 2) + r;
      float s = 0.f;
      #pragma unroll
      for (int ni = 0; ni < 4; ni++){
        int col = n0 + wn + ni*16 + (lane & 15);
        s += __expf(acc[mi][ni][r] + bv[col]);
      }
      s += __shfl_xor(s, 1);
      s += __shfl_xor(s, 2);
      s += __shfl_xor(s, 4);
      s += __shfl_xor(s, 8);
      if ((lane & 15) == 0) atomicAdd(&rowsum[row], s);
    }
  }
}

// fused: tn = tanh(e_null @ W1 + b1); p0 = sigmoid(tn . Wp + bp) * 0.3
__global__ void k_tnp0(const int* __restrict__ tnull, const float* __restrict__ emb,
                       const float* __restrict__ W1, const float* __restrict__ b1,
                       const float* __restrict__ Wp, const float* __restrict__ bp,
                       float* __restrict__ tn, float* __restrict__ p0){
  __shared__ float en[E_];
  __shared__ float red[512];
  int t = threadIdx.x;                 // 512
  if (t < E_) en[t] = emb[(long long)tnull[0]*E_ + t];
  __syncthreads();
  float s = b1[t];
  for (int e = 0; e < E_; e++) s += en[e]*W1[(long long)e*H_ + t];
  float v = tanhf(s);
  tn[t] = v;
  red[t] = v*Wp[t];
  __syncthreads();
  for (int w = 256; w > 0; w >>= 1){
    if (t < w) red[t] += red[t+w];
    __syncthreads();
  }
  if (t == 0) p0[0] = sigf(red[0] + bp[0])*0.3f;
}

__global__ void k_nullrow(const float* __restrict__ tn, const float* __restrict__ Wv,
                          const float* __restrict__ bv, float* __restrict__ lognull,
                          float* __restrict__ nullsum){
  __shared__ float tns[H_];
  __shared__ float red[256];
  int tid = threadIdx.x;
  tns[tid] = tn[tid]; tns[tid+256] = tn[tid+256];
  __syncthreads();
  int c = blockIdx.x*256 + tid;
  float s = bv[c];
  for (int k = 0; k < H_; k++) s += tns[k]*Wv[(long long)k*VS_ + c];
  lognull[c] = s;
  red[tid] = __expf(s);
  __syncthreads();
  for (int w = 128; w > 0; w >>= 1){
    if (tid < w) red[tid] += red[tid+w];
    __syncthreads();
  }
  if (tid == 0) atomicAdd(nullsum, red[0]);
}

__global__ void k_gather(const int* __restrict__ sources, const float* __restrict__ Wv,
                         const float* __restrict__ bv, float* __restrict__ WgT,
                         float* __restrict__ bg){
  int bk = blockIdx.x;           // b*H_ + k
  int b = bk >> 9, k = bk & 511;
  int i = threadIdx.x;
  if (i >= I_) return;
  int s = sources[b*I_ + i];
  WgT[((long long)b*H_ + k)*I_ + i] = Wv[(long long)k*VS_ + s];
  if (k == 0) bg[b*I_ + i] = bv[s];
}

__global__ void k_emission(const float* __restrict__ gl, const float* __restrict__ rowsum,
                           const float* __restrict__ lognull, const float* __restrict__ nullsum,
                           const int* __restrict__ sources, float* __restrict__ out_em){
  int bx = blockIdx.x;           // b*192 + jj
  int b = bx / 192, jj = bx % 192;
  int i = threadIdx.x;
  if (i >= I_) return;
  float v;
  if (jj < J_) v = __expf(gl[((long long)b*J_ + jj)*I_ + i]) / rowsum[b*J_ + jj];
  else { int s = sources[b*I_ + i]; v = __expf(lognull[s]) / nullsum[0]; }
  out_em[(long long)bx*I_ + i] = v;
}

__global__ void k_transition(const float* __restrict__ jlog, const float* __restrict__ p0p,
                             float* __restrict__ T, float* __restrict__ TL){
  int bx = blockIdx.x;           // b*J_ + j
  int b = bx / J_, j = bx % J_;
  int tid = threadIdx.x;         // 128
  __shared__ float ex[128];
  __shared__ float red[128];
  float e = 0.f;
  if (tid < 96) e = __expf(jlog[(long long)bx*SJ_ + (96 - j + tid)]);
  ex[tid] = e; red[tid] = e;
  __syncthreads();
  for (int w = 64; w > 0; w >>= 1){
    if (tid < w) red[tid] += red[tid+w];
    __syncthreads();
  }
  float p0 = p0p[0];
  float scale = (1.f - p0) / red[0];
  float lp0 = logf(p0);
  long long r0 = ((long long)b*192 + j)*192;
  long long r1 = ((long long)b*192 + j + 96)*192;
  for (int col = tid; col < 192; col += 128){
    float tv, lv;
    if (col < 96){ tv = ex[col]*scale; lv = logf(tv); }
    else { bool d = (col - 96) == j; tv = d ? p0 : 0.f; lv = d ? lp0 : 0.f; }
    T[r0 + col] = tv; T[r1 + col] = tv;
    TL[r0 + col] = lv; TL[r1 + col] = lv;
  }
}

extern "C" void kernel_launch(void* const* d_in, const int* in_sizes, int n_in,
                              void* d_out, int out_size, void* d_ws, size_t ws_size,
                              hipStream_t stream)
{
  const int* sources = (const int*)d_in[0];
  const int* targets = (const int*)d_in[1];
  const int* tnull   = (const int*)d_in[2];
  const float* emb   = (const float*)d_in[3];
  const float* Wfw   = (const float*)d_in[4];
  const float* bfw   = (const float*)d_in[5];
  const float* Wbw   = (const float*)d_in[6];
  const float* bbw   = (const float*)d_in[7];
  const float* Wl    = (const float*)d_in[8];
  const float* W1    = (const float*)d_in[9];
  const float* b1    = (const float*)d_in[10];
  const float* Wv    = (const float*)d_in[11];
  const float* bv    = (const float*)d_in[12];
  const float* Wj    = (const float*)d_in[13];
  const float* bj    = (const float*)d_in[14];
  const float* Wp    = (const float*)d_in[15];
  const float* bp    = (const float*)d_in[16];
  float* out = (float*)d_out;
  float* ws  = (float*)d_ws;

  long long off = 0;
  float* e_word = ws + off; off += (long long)NROW*E_;
  float* Xfw    = ws + off; off += (long long)NROW*2048;
  float* Xbw    = ws + off; off += (long long)NROW*2048;
  float* Hcat   = ws + off; off += (long long)NROW*1024;
  unsigned int* hex32 = (unsigned int*)(ws + off); off += 2*2*16*256;  // 16384 words
  unsigned int* flags = (unsigned int*)(ws + off); off += 128;
  float* ts     = ws + off; off += (long long)NROW*E_;
  float* t1     = ws + off; off += (long long)NROW*H_;
  unsigned short* t1h = (unsigned short*)(ws + off); off += (long long)NROW*H_/2;
  float* tn     = ws + off; off += H_;
  float* rowsum = ws + off; off += NROW;
  float* nullsum= ws + off; off += 1;
  float* p0     = ws + off; off += 1;
  float* gl     = ws + off; off += (long long)NROW*I_;
  float* WgT    = ws + off; off += (long long)B_*H_*I_;
  float* bg     = ws + off; off += B_*I_;
  float* lognull= ws + off; off += VS_;
  float* jlog   = ws + off; off += (long long)NROW*SJ_;
  unsigned short* WvT = (unsigned short*)(ws + off); off += (long long)VS_*H_/2;

  float* out_em = out;
  float* out_T  = out + (long long)B_*192*96;
  float* out_TL = out_T + (long long)B_*192*192;

  // per-call init: h-exchange + flags, rowsum + nullsum
  k_init<<<65, 256, 0, stream>>>(hex32, rowsum);

  k_embed<<<NROW, 256, 0, stream>>>(targets, emb, e_word);

  // Wv -> bf16 transposed (for MFMA GEMM)
  k_wvt<<<dim3(VS_/64, H_/64), 256, 0, stream>>>(Wv, WvT);

  // input projections for both directions: [1536,256] @ [256,2048] + b
  dim3 gx(2048/64, NROW/64);
  k_gemm<0><<<gx, 256, 0, stream>>>(e_word, E_, 0, Wfw, 2048, 0, Xfw, 2048, 0,
                                    NROW, 2048, E_, bfw, 0, nullptr);
  k_gemm<0><<<gx, 256, 0, stream>>>(e_word, E_, 0, Wbw, 2048, 0, Xbw, 2048, 0,
                                    NROW, 2048, E_, bbw, 0, nullptr);

  // persistent fence-free bi-LSTM
  k_lstm3<<<128, 256, 0, stream>>>(Xfw, Xbw, Wfw, Wbw, hex32, flags, Hcat);

  // ts = Hcat @ W_lstm   [1536,1024]@[1024,256]
  k_gemm<0><<<dim3(E_/64, NROW/64), 256, 0, stream>>>(Hcat, 2*H_, 0, Wl, E_, 0,
                                                      ts, E_, 0, NROW, E_, 2*H_,
                                                      nullptr, 0, nullptr);
  // t1 = tanh(ts @ W1 + b1)   [1536,256]@[256,512]  (+ bf16 copy t1h)
  k_gemm<1><<<dim3(H_/64, NROW/64), 256, 0, stream>>>(ts, E_, 0, W1, H_, 0,
                                                      t1, H_, 0, NROW, H_, E_,
                                                      b1, 0, t1h);

  k_tnp0<<<1, 512, 0, stream>>>(tnull, emb, W1, b1, Wp, bp, tn, p0);
  k_nullrow<<<VS_/256, 256, 0, stream>>>(tn, Wv, bv, lognull, nullsum);
  k_gather<<<B_*H_, 128, 0, stream>>>(sources, Wv, bv, WgT, bg);

  // rowsum[m] = sum_n exp(logits) via bf16 MFMA GEMM
  k_vgemm<<<3000, 256, 0, stream>>>(t1h, WvT, bv, rowsum);

  // gathered logits: per-batch [96,512]@[512,96] + gathered bias (fp32)
  k_gemm<0><<<dim3(2, 2, B_), 256, 0, stream>>>(t1, H_, (long long)J_*H_,
                                                WgT, I_, (long long)H_*I_,
                                                gl, I_, (long long)J_*I_,
                                                J_, I_, H_, bg, I_, nullptr);
  // jump logits: [1536,512]@[512,193] + bj
  k_gemm<0><<<dim3(4, NROW/64), 256, 0, stream>>>(t1, H_, 0, Wj, SJ_, 0,
                                                  jlog, SJ_, 0, NROW, SJ_, H_,
                                                  bj, 0, nullptr);

  k_emission<<<B_*192, 128, 0, stream>>>(gl, rowsum, lognull, nullsum, sources, out_em);
  k_transition<<<NROW, 128, 0, stream>>>(jlog, p0, out_T, out_TL);
}

// Round 6
// 884.605 us; speedup vs baseline: 6.5778x; 1.0184x over previous
//
#include <hip/hip_runtime.h>
#include <math.h>

#define B_ 16
#define J_ 96
#define I_ 96
#define E_ 256
#define H_ 512
#define VS_ 32000
#define SJ_ 193
#define NROW (B_*J_)   // 1536

typedef __attribute__((ext_vector_type(8))) short short8;
typedef __attribute__((ext_vector_type(4))) float f32x4;
typedef __attribute__((ext_vector_type(4))) unsigned int u32x4;

__device__ __forceinline__ float sigf(float x){ return 1.f/(1.f+__expf(-x)); }

__device__ __forceinline__ unsigned short f2bf(float x){
  unsigned int u = __float_as_uint(x);
  unsigned int r = (u + 0x7FFFu + ((u>>16)&1u)) >> 16;
  return (unsigned short)r;
}

#define ASYNC16(gp, lp) __builtin_amdgcn_global_load_lds( \
    (const __attribute__((address_space(1))) unsigned int*)(gp), \
    (__attribute__((address_space(3))) unsigned int*)(lp), 16, 0, 0)

// zero h-exchange (16384 u32) + flags (128 u32) contiguous, and rowsum/nullsum
__global__ void k_init(unsigned int* __restrict__ hexflags, float* __restrict__ rowsum){
  int i = blockIdx.x*256 + threadIdx.x;
  if (i < 16384 + 128) hexflags[i] = 0u;
  if (i < NROW + 1) rowsum[i] = 0.f;
}

__global__ void k_embed(const int* __restrict__ targets, const float* __restrict__ emb,
                        float* __restrict__ e_word){
  int row = blockIdx.x;
  int t = targets[row];
  e_word[(long long)row*E_ + threadIdx.x] = emb[(long long)t*E_ + threadIdx.x];
}

// Generic 64x64 tiled fp32 GEMM. EPI: 0 = C=A@B+bias, 1 = tanh(A@B+bias) (+bf16 copy)
template<int EPI>
__global__ void k_gemm(const float* __restrict__ A, int lda, long long sA,
                       const float* __restrict__ B, int ldb, long long sB,
                       float* __restrict__ C, int ldc, long long sC,
                       int M, int N, int K,
                       const float* __restrict__ bias, long long sBias,
                       unsigned short* __restrict__ Ch)
{
  const int bz = blockIdx.z;
  A += (long long)bz*sA; B += (long long)bz*sB;
  if (C) C += (long long)bz*sC;
  if (bias) bias += (long long)bz*sBias;
  const int m0 = blockIdx.y*64, n0 = blockIdx.x*64;
  __shared__ float As[16][68];
  __shared__ float Bs[16][68];
  const int tid = threadIdx.x;         // 256
  const int tx = tid & 15, ty = tid >> 4;
  float acc[4][4] = {};
  for (int k0 = 0; k0 < K; k0 += 16){
    {
      const int kk = tid & 15, r0 = tid >> 4;
      #pragma unroll
      for (int i = 0; i < 4; i++){
        int rr = r0 + i*16, m = m0 + rr;
        As[kk][rr] = (m < M) ? A[(long long)m*lda + k0 + kk] : 0.f;
      }
    }
    {
      const int c = tid & 63, k4 = tid >> 6;
      #pragma unroll
      for (int i = 0; i < 4; i++){
        int kk = k4 + i*4, n = n0 + c;
        Bs[kk][c] = (n < N) ? B[(long long)(k0+kk)*ldb + n] : 0.f;
      }
    }
    __syncthreads();
    #pragma unroll
    for (int kk = 0; kk < 16; kk++){
      float a[4], b[4];
      #pragma unroll
      for (int i = 0; i < 4; i++) a[i] = As[kk][ty*4 + i];
      #pragma unroll
      for (int j = 0; j < 4; j++) b[j] = Bs[kk][tx*4 + j];
      #pragma unroll
      for (int i = 0; i < 4; i++)
        #pragma unroll
        for (int j = 0; j < 4; j++)
          acc[i][j] += a[i]*b[j];
    }
    __syncthreads();
  }
  #pragma unroll
  for (int i = 0; i < 4; i++){
    int m = m0 + ty*4 + i;
    if (m >= M) continue;
    #pragma unroll
    for (int j = 0; j < 4; j++){
      int n = n0 + tx*4 + j;
      if (n >= N) continue;
      float v = acc[i][j] + (bias ? bias[n] : 0.f);
      if (EPI == 1) v = tanhf(v);
      C[(long long)m*ldc + n] = v;
      if (EPI == 1 && Ch) Ch[(long long)m*ldc + n] = f2bf(v);
    }
  }
}

// ---------------------------------------------------------------------------
// Persistent bi-LSTM v5: r4-proven flag protocol, trimmed critical path.
// 128 blocks x 256 thr (64/dir), each owns 8 hidden units (32 gate cols).
// Per step: X prefetch -> poll flags -> 4x 16B sc0/sc1 A-loads -> 8 MFMAs
// (B-frags in regs) -> z_s[parity] write -> ONE barrier -> wave0 only:
// gates (2 units/lane) -> h u32 store (atomic relaxed agent) -> wave-local
// vmcnt(0) -> lane0 flag store -> Hcat.
// hex: [dir][par][16 batch][512 h bf16] = dir*32768B. flags: [dir][64].
// Safety: z_s parity-dbuf makes the single barrier safe (flag chain ensures
// step-s readers of z_s[par] finish before any step-s+2 writer of z_s[par]).
// ---------------------------------------------------------------------------
__global__ __launch_bounds__(256, 2) void k_lstm5(
    const float* __restrict__ Xfw, const float* __restrict__ Xbw,
    const float* __restrict__ Wfw, const float* __restrict__ Wbw,
    unsigned int* __restrict__ hex32,
    unsigned int* __restrict__ flags,
    float* __restrict__ Hcat)
{
  __shared__ unsigned short W_s[32*512];    // 32 KB, [col][k] bf16, XOR-swizzled
  __shared__ float z_s[2][4][16][36];       // parity-dbuf per-quarter partials
  const int bid = blockIdx.x;               // 0..127
  const int dir = bid >> 6;
  const int slice = bid & 63;
  const int u0 = slice * 8;
  const int t = threadIdx.x;                // 0..255
  const int lane = t & 63;
  const int q = t >> 6;                     // wave = K-quarter
  const int m = lane & 15, hi = lane >> 4;
  const float* X = dir ? Xbw : Xfw;
  const float* Wg = (dir ? Wbw : Wfw) + (long long)E_*2048;
  char* hexd = (char*)hex32 + dir*32768;    // per-dir: 2 par x 16 KB
  unsigned int* flg = flags + dir*64;

  // ---- stage W slice -> LDS bf16 [col][k], 16B-block XOR swizzle ----
  for (int rep = 0; rep < 8; rep++){
    int id = rep*256 + t;                   // 0..2047
    int k = id >> 2, g = id & 3;
    const float* src = Wg + (long long)k*2048 + g*512 + u0;
    float4 w0 = *(const float4*)src;
    float4 w1 = *(const float4*)(src + 4);
    float wv8[8] = {w0.x,w0.y,w0.z,w0.w,w1.x,w1.y,w1.z,w1.w};
    #pragma unroll
    for (int uu = 0; uu < 8; uu++){
      int c = g*8 + uu;
      int byte = (c << 10) + (k << 1);
      byte ^= ((c & 7) << 4);
      *(unsigned short*)((char*)W_s + byte) = f2bf(wv8[uu]);
    }
  }
  __syncthreads();

  // ---- hoist B-fragments (loop-invariant across all 96 steps) ----
  short8 bfr[2][4];
  #pragma unroll
  for (int nt = 0; nt < 2; nt++)
    #pragma unroll
    for (int ck = 0; ck < 4; ck++){
      int col = nt*16 + m;
      int kc = q*4 + ck;
      int byte = (col << 10) + kc*64 + hi*16;
      byte ^= ((col & 7) << 4);
      bfr[nt][ck] = *(const short8*)((const char*)W_s + byte);
    }

  // wave-0 gate mapping: lane -> (batch eb, unit pair u0+eu2, u0+eu2+1)
  const int eb = lane >> 2, eu2 = (lane & 3)*2;
  float creg0 = 0.f, creg1 = 0.f;

  for (int step = 0; step < J_; step++){
    const int par = step & 1;
    const int t_eff = dir ? (J_-1-step) : step;
    // X prefetch BEFORE poll (latency hides under the spin); wave 0 only
    float2 xg0 = {0.f,0.f}, xg1 = {0.f,0.f}, xg2 = {0.f,0.f}, xg3 = {0.f,0.f};
    if (q == 0){
      const float* xr = X + ((long long)eb*J_ + t_eff)*2048 + u0 + eu2;
      xg0 = *(const float2*)(xr);
      xg1 = *(const float2*)(xr + 512);
      xg2 = *(const float2*)(xr + 1024);
      xg3 = *(const float2*)(xr + 1536);
    }
    if (step > 0){
      for (;;){
        unsigned int v = __hip_atomic_load(&flg[lane], __ATOMIC_RELAXED,
                                           __HIP_MEMORY_SCOPE_AGENT);
        if (__all((int)(v >= (unsigned)step))) break;
        __builtin_amdgcn_s_sleep(1);
      }
    }
    __builtin_amdgcn_sched_barrier(0);
    // A-fragment loads: 16B each, from coherence point (r4-proven pattern)
    const char* ap = hexd + par*16384 + m*1024 + q*256 + hi*16;
    u32x4 d0, d1, d2, d3;
    asm volatile("global_load_dwordx4 %0, %1, off sc0 sc1" : "=v"(d0) : "v"(ap));
    asm volatile("global_load_dwordx4 %0, %1, off offset:64 sc0 sc1" : "=v"(d1) : "v"(ap));
    asm volatile("global_load_dwordx4 %0, %1, off offset:128 sc0 sc1" : "=v"(d2) : "v"(ap));
    asm volatile("global_load_dwordx4 %0, %1, off offset:192 sc0 sc1" : "=v"(d3) : "v"(ap));
    asm volatile("s_waitcnt vmcnt(0)" ::: "memory");
    __builtin_amdgcn_sched_barrier(0);
    union { u32x4 u; short8 s; } a0, a1, a2, a3;
    a0.u = d0; a1.u = d1; a2.u = d2; a3.u = d3;
    f32x4 acc0 = {0.f,0.f,0.f,0.f}, acc1 = {0.f,0.f,0.f,0.f};
    acc0 = __builtin_amdgcn_mfma_f32_16x16x32_bf16(a0.s, bfr[0][0], acc0, 0,0,0);
    acc1 = __builtin_amdgcn_mfma_f32_16x16x32_bf16(a0.s, bfr[1][0], acc1, 0,0,0);
    acc0 = __builtin_amdgcn_mfma_f32_16x16x32_bf16(a1.s, bfr[0][1], acc0, 0,0,0);
    acc1 = __builtin_amdgcn_mfma_f32_16x16x32_bf16(a1.s, bfr[1][1], acc1, 0,0,0);
    acc0 = __builtin_amdgcn_mfma_f32_16x16x32_bf16(a2.s, bfr[0][2], acc0, 0,0,0);
    acc1 = __builtin_amdgcn_mfma_f32_16x16x32_bf16(a2.s, bfr[1][2], acc1, 0,0,0);
    acc0 = __builtin_amdgcn_mfma_f32_16x16x32_bf16(a3.s, bfr[0][3], acc0, 0,0,0);
    acc1 = __builtin_amdgcn_mfma_f32_16x16x32_bf16(a3.s, bfr[1][3], acc1, 0,0,0);
    #pragma unroll
    for (int r = 0; r < 4; r++){
      z_s[par][q][hi*4 + r][m]      = acc0[r];
      z_s[par][q][hi*4 + r][16 + m] = acc1[r];
    }
    __syncthreads();                  // single barrier per step
    if (q == 0){
      float zi0 = xg0.x, zi1 = xg0.y;
      float zg0 = xg1.x, zg1 = xg1.y;
      float zf0 = xg2.x, zf1 = xg2.y;
      float zo0 = xg3.x, zo1 = xg3.y;
      #pragma unroll
      for (int qq = 0; qq < 4; qq++){
        zi0 += z_s[par][qq][eb][eu2];      zi1 += z_s[par][qq][eb][eu2+1];
        zg0 += z_s[par][qq][eb][8 + eu2];  zg1 += z_s[par][qq][eb][8 + eu2+1];
        zf0 += z_s[par][qq][eb][16 + eu2]; zf1 += z_s[par][qq][eb][16 + eu2+1];
        zo0 += z_s[par][qq][eb][24 + eu2]; zo1 += z_s[par][qq][eb][24 + eu2+1];
      }
      creg0 = sigf(zf0 + 1.f)*creg0 + sigf(zi0)*tanhf(zg0);
      creg1 = sigf(zf1 + 1.f)*creg1 + sigf(zi1)*tanhf(zg1);
      float h0 = sigf(zo0)*tanhf(creg0);
      float h1 = sigf(zo1)*tanhf(creg1);
      unsigned int pack = (unsigned int)f2bf(h0) | ((unsigned int)f2bf(h1) << 16);
      __hip_atomic_store((unsigned int*)(hexd + (par^1)*16384 + eb*1024 + (u0 + eu2)*2),
                         pack, __ATOMIC_RELAXED, __HIP_MEMORY_SCOPE_AGENT);
      asm volatile("s_waitcnt vmcnt(0)" ::: "memory");   // wave-local drain of h stores
      if (lane == 0)
        __hip_atomic_store(&flg[slice], (unsigned int)(step+1),
                           __ATOMIC_RELAXED, __HIP_MEMORY_SCOPE_AGENT);
      float2 hp = {h0, h1};
      *(float2*)&Hcat[((long long)eb*J_ + t_eff)*1024 + dir*512 + u0 + eu2] = hp;
    }
  }
}

// Wv fp32 [512][32000] -> WvT bf16 [32000][512]
__global__ void k_wvt(const float* __restrict__ Wv, unsigned short* __restrict__ WvT){
  __shared__ float tile[64][65];
  int n0 = blockIdx.x*64, k0 = blockIdx.y*64;
  int t = threadIdx.x;
  for (int rep = 0; rep < 16; rep++){
    int idx = rep*256 + t;
    int kk = idx >> 6, nn = idx & 63;
    tile[kk][nn] = Wv[(long long)(k0+kk)*VS_ + n0 + nn];
  }
  __syncthreads();
  for (int rep = 0; rep < 16; rep++){
    int idx = rep*256 + t;
    int nn = idx >> 6, kk = idx & 63;
    WvT[(long long)(n0+nn)*H_ + k0 + kk] = f2bf(tile[kk][nn]);
  }
}

// bf16 MFMA GEMM: rowsum[m] += sum_n exp( A[1536,512] @ WvT[n][512]^T + bv[n] )
__global__ __launch_bounds__(256, 2) void k_vgemm(
    const unsigned short* __restrict__ Ah,    // [1536][512]
    const unsigned short* __restrict__ Bh,    // [32000][512]
    const float* __restrict__ bv,
    float* __restrict__ rowsum)
{
  __shared__ unsigned short As[128*32];
  __shared__ unsigned short Bs[128*32];
  // bijective XCD swizzle: 3000 = 8 * 375
  int braw = blockIdx.x;
  int wg = (braw & 7)*375 + (braw >> 3);
  int mt = wg % 12, nt = wg / 12;
  const int m0 = mt*128, n0 = nt*128;
  const int t = threadIdx.x;
  const int lane = t & 63, w = t >> 6;
  const int wm = (w >> 1)*64, wn = (w & 1)*64;
  f32x4 acc[4][4] = {};
  for (int k0 = 0; k0 < 512; k0 += 32){
    #pragma unroll
    for (int p = 0; p < 2; p++){
      int rowA = p*64 + (t >> 2);
      int kc = (t & 3) ^ ((rowA >> 1) & 3);
      const unsigned short* ga = Ah + (long long)(m0 + rowA)*512 + k0 + kc*8;
      const unsigned short* gb = Bh + (long long)(n0 + rowA)*512 + k0 + kc*8;
      unsigned short* la = As + p*2048 + w*512;
      unsigned short* lb = Bs + p*2048 + w*512;
      ASYNC16(ga, la);
      ASYNC16(gb, lb);
    }
    __syncthreads();
    short8 af[4], bf[4];
    const int rr = lane & 15, kch = lane >> 4;
    #pragma unroll
    for (int mi = 0; mi < 4; mi++){
      int rowA = wm + mi*16 + rr;
      int slot = kch ^ ((rowA >> 1) & 3);
      af[mi] = *(const short8*)&As[rowA*32 + slot*8];
    }
    #pragma unroll
    for (int ni = 0; ni < 4; ni++){
      int rowB = wn + ni*16 + rr;
      int slot = kch ^ ((rowB >> 1) & 3);
      bf[ni] = *(const short8*)&Bs[rowB*32 + slot*8];
    }
    #pragma unroll
    for (int mi = 0; mi < 4; mi++)
      #pragma unroll
      for (int ni = 0; ni < 4; ni++)
        acc[mi][ni] = __builtin_amdgcn_mfma_f32_16x16x32_bf16(af[mi], bf[ni], acc[mi][ni], 0, 0, 0);
    __syncthreads();
  }
  #pragma unroll
  for (int mi = 0; mi < 4; mi++){
    #pragma unroll
    for (int r = 0; r < 4; r++){
      int row = m0 + wm + mi*16 + ((lane >> 4) << 2) + r;
      float s = 0.f;
      #pragma unroll
      for (int ni = 0; ni < 4; ni++){
        int col = n0 + wn + ni*16 + (lane & 15);
        s += __expf(acc[mi][ni][r] + bv[col]);
      }
      s += __shfl_xor(s, 1);
      s += __shfl_xor(s, 2);
      s += __shfl_xor(s, 4);
      s += __shfl_xor(s, 8);
      if ((lane & 15) == 0) atomicAdd(&rowsum[row], s);
    }
  }
}

// gathered-logits GEMM + word-emission epilogue. One block per batch.
// em[b][j][i] = exp( t1[b*96+j] . WvT[src[b][i]] + bv[src] ) / rowsum[b*96+j]
__global__ __launch_bounds__(256, 2) void k_glgemm(
    const unsigned short* __restrict__ t1h,   // [1536][512]
    const unsigned short* __restrict__ WvT,   // [32000][512]
    const float* __restrict__ bv,
    const int* __restrict__ sources,          // [16][96]
    const float* __restrict__ rowsum,         // [1536]
    float* __restrict__ out_em)               // [16][192][96]
{
  __shared__ int   srcs[96];
  __shared__ float bgs[96];
  const int b = blockIdx.x;
  const int t = threadIdx.x, lane = t & 63, w = t >> 6;
  if (t < 96){ int s = sources[b*96 + t]; srcs[t] = s; bgs[t] = bv[s]; }
  __syncthreads();
  const int rr = lane & 15, kq = lane >> 4;
  for (int tile = w; tile < 36; tile += 4){
    int mt = tile / 6, nt = tile % 6;
    const unsigned short* arow = t1h + ((long long)(b*96 + mt*16 + rr))*512 + kq*8;
    const unsigned short* brow = WvT + (long long)srcs[nt*16 + rr]*512 + kq*8;
    f32x4 acc = {0.f,0.f,0.f,0.f};
    #pragma unroll
    for (int kc = 0; kc < 16; kc++){
      short8 af = *(const short8*)(arow + kc*32);
      short8 bf = *(const short8*)(brow + kc*32);
      acc = __builtin_amdgcn_mfma_f32_16x16x32_bf16(af, bf, acc, 0, 0, 0);
    }
    #pragma unroll
    for (int r = 0; r < 4; r++){
      int j = mt*16 + kq*4 + r;
      int i = nt*16 + rr;
      float v = __expf(acc[r] + bgs[i]) / rowsum[b*96 + j];
      out_em[((long long)b*192 + j)*96 + i] = v;
    }
  }
}

// fused: tn = tanh(e_null @ W1 + b1); p0 = sigmoid(tn . Wp + bp) * 0.3
__global__ void k_tnp0(const int* __restrict__ tnull, const float* __restrict__ emb,
                       const float* __restrict__ W1, const float* __restrict__ b1,
                       const float* __restrict__ Wp, const float* __restrict__ bp,
                       float* __restrict__ tn, float* __restrict__ p0){
  __shared__ float en[E_];
  __shared__ float red[512];
  int t = threadIdx.x;                 // 512
  if (t < E_) en[t] = emb[(long long)tnull[0]*E_ + t];
  __syncthreads();
  float s = b1[t];
  for (int e = 0; e < E_; e++) s += en[e]*W1[(long long)e*H_ + t];
  float v = tanhf(s);
  tn[t] = v;
  red[t] = v*Wp[t];
  __syncthreads();
  for (int w = 256; w > 0; w >>= 1){
    if (t < w) red[t] += red[t+w];
    __syncthreads();
  }
  if (t == 0) p0[0] = sigf(red[0] + bp[0])*0.3f;
}

__global__ void k_nullrow(const float* __restrict__ tn, const float* __restrict__ Wv,
                          const float* __restrict__ bv, float* __restrict__ lognull,
                          float* __restrict__ nullsum){
  __shared__ float tns[H_];
  __shared__ float red[256];
  int tid = threadIdx.x;
  tns[tid] = tn[tid]; tns[tid+256] = tn[tid+256];
  __syncthreads();
  int c = blockIdx.x*256 + tid;
  float s = bv[c];
  for (int k = 0; k < H_; k++) s += tns[k]*Wv[(long long)k*VS_ + c];
  lognull[c] = s;
  red[tid] = __expf(s);
  __syncthreads();
  for (int w = 128; w > 0; w >>= 1){
    if (tid < w) red[tid] += red[tid+w];
    __syncthreads();
  }
  if (tid == 0) atomicAdd(nullsum, red[0]);
}

// null half of emission: 96 identical rows per batch
__global__ void k_emission_null(const float* __restrict__ lognull,
                                const float* __restrict__ nullsum,
                                const int* __restrict__ sources,
                                float* __restrict__ out_em){
  int b = blockIdx.x;
  int i = threadIdx.x;
  if (i >= 96) return;
  int s = sources[b*96 + i];
  float v = __expf(lognull[s]) / nullsum[0];
  for (int jj = 0; jj < 96; jj++)
    out_em[((long long)b*192 + 96 + jj)*96 + i] = v;
}

__global__ void k_transition(const float* __restrict__ jlog, const float* __restrict__ p0p,
                             float* __restrict__ T, float* __restrict__ TL){
  int bx = blockIdx.x;           // b*J_ + j
  int b = bx / J_, j = bx % J_;
  int tid = threadIdx.x;         // 128
  __shared__ float ex[128];
  __shared__ float red[128];
  float e = 0.f;
  if (tid < 96) e = __expf(jlog[(long long)bx*SJ_ + (96 - j + tid)]);
  ex[tid] = e; red[tid] = e;
  __syncthreads();
  for (int w = 64; w > 0; w >>= 1){
    if (tid < w) red[tid] += red[tid+w];
    __syncthreads();
  }
  float p0 = p0p[0];
  float scale = (1.f - p0) / red[0];
  float lp0 = logf(p0);
  long long r0 = ((long long)b*192 + j)*192;
  long long r1 = ((long long)b*192 + j + 96)*192;
  for (int col = tid; col < 192; col += 128){
    float tv, lv;
    if (col < 96){ tv = ex[col]*scale; lv = logf(tv); }
    else { bool d = (col - 96) == j; tv = d ? p0 : 0.f; lv = d ? lp0 : 0.f; }
    T[r0 + col] = tv; T[r1 + col] = tv;
    TL[r0 + col] = lv; TL[r1 + col] = lv;
  }
}

extern "C" void kernel_launch(void* const* d_in, const int* in_sizes, int n_in,
                              void* d_out, int out_size, void* d_ws, size_t ws_size,
                              hipStream_t stream)
{
  const int* sources = (const int*)d_in[0];
  const int* targets = (const int*)d_in[1];
  const int* tnull   = (const int*)d_in[2];
  const float* emb   = (const float*)d_in[3];
  const float* Wfw   = (const float*)d_in[4];
  const float* bfw   = (const float*)d_in[5];
  const float* Wbw   = (const float*)d_in[6];
  const float* bbw   = (const float*)d_in[7];
  const float* Wl    = (const float*)d_in[8];
  const float* W1    = (const float*)d_in[9];
  const float* b1    = (const float*)d_in[10];
  const float* Wv    = (const float*)d_in[11];
  const float* bv    = (const float*)d_in[12];
  const float* Wj    = (const float*)d_in[13];
  const float* bj    = (const float*)d_in[14];
  const float* Wp    = (const float*)d_in[15];
  const float* bp    = (const float*)d_in[16];
  float* out = (float*)d_out;
  float* ws  = (float*)d_ws;

  long long off = 0;
  float* e_word = ws + off; off += (long long)NROW*E_;
  float* Xfw    = ws + off; off += (long long)NROW*2048;
  float* Xbw    = ws + off; off += (long long)NROW*2048;
  float* Hcat   = ws + off; off += (long long)NROW*1024;
  unsigned int* hex32 = (unsigned int*)(ws + off); off += 16384;  // [2dir][2par][16][256] u32
  unsigned int* flags = (unsigned int*)(ws + off); off += 128;    // contiguous after hex
  float* ts     = ws + off; off += (long long)NROW*E_;
  float* t1     = ws + off; off += (long long)NROW*H_;
  unsigned short* t1h = (unsigned short*)(ws + off); off += (long long)NROW*H_/2;
  float* tn     = ws + off; off += H_;
  float* rowsum = ws + off; off += NROW;
  float* nullsum= ws + off; off += 1;
  float* p0     = ws + off; off += 1;
  float* lognull= ws + off; off += VS_;
  float* jlog   = ws + off; off += (long long)NROW*SJ_;
  unsigned short* WvT = (unsigned short*)(ws + off); off += (long long)VS_*H_/2;

  float* out_em = out;
  float* out_T  = out + (long long)B_*192*96;
  float* out_TL = out_T + (long long)B_*192*192;

  // per-call init: h-exchange + flags (tags/state), rowsum + nullsum
  k_init<<<65, 256, 0, stream>>>(hex32, rowsum);

  k_tnp0<<<1, 512, 0, stream>>>(tnull, emb, W1, b1, Wp, bp, tn, p0);
  k_embed<<<NROW, 256, 0, stream>>>(targets, emb, e_word);

  // Wv -> bf16 transposed (for MFMA GEMMs)
  k_wvt<<<dim3(VS_/64, H_/64), 256, 0, stream>>>(Wv, WvT);

  // input projections for both directions: [1536,256] @ [256,2048] + b
  dim3 gx(2048/64, NROW/64);
  k_gemm<0><<<gx, 256, 0, stream>>>(e_word, E_, 0, Wfw, 2048, 0, Xfw, 2048, 0,
                                    NROW, 2048, E_, bfw, 0, nullptr);
  k_gemm<0><<<gx, 256, 0, stream>>>(e_word, E_, 0, Wbw, 2048, 0, Xbw, 2048, 0,
                                    NROW, 2048, E_, bbw, 0, nullptr);

  // persistent flag-protocol bi-LSTM
  k_lstm5<<<128, 256, 0, stream>>>(Xfw, Xbw, Wfw, Wbw, hex32, flags, Hcat);

  // ts = Hcat @ W_lstm   [1536,1024]@[1024,256]
  k_gemm<0><<<dim3(E_/64, NROW/64), 256, 0, stream>>>(Hcat, 2*H_, 0, Wl, E_, 0,
                                                      ts, E_, 0, NROW, E_, 2*H_,
                                                      nullptr, 0, nullptr);
  // t1 = tanh(ts @ W1 + b1)   [1536,256]@[256,512]  (+ bf16 copy t1h)
  k_gemm<1><<<dim3(H_/64, NROW/64), 256, 0, stream>>>(ts, E_, 0, W1, H_, 0,
                                                      t1, H_, 0, NROW, H_, E_,
                                                      b1, 0, t1h);

  k_nullrow<<<VS_/256, 256, 0, stream>>>(tn, Wv, bv, lognull, nullsum);

  // rowsum[m] = sum_n exp(logits) via bf16 MFMA GEMM
  k_vgemm<<<3000, 256, 0, stream>>>(t1h, WvT, bv, rowsum);

  // gathered logits + word emission (fused)
  k_glgemm<<<B_, 256, 0, stream>>>(t1h, WvT, bv, sources, rowsum, out_em);

  // jump logits: [1536,512]@[512,193] + bj
  k_gemm<0><<<dim3(4, NROW/64), 256, 0, stream>>>(t1, H_, 0, Wj, SJ_, 0,
                                                  jlog, SJ_, 0, NROW, SJ_, H_,
                                                  bj, 0, nullptr);

  k_emission_null<<<B_, 128, 0, stream>>>(lognull, nullsum, sources, out_em);
  k_transition<<<NROW, 128, 0, stream>>>(jlog, p0, out_T, out_TL);
}

// Round 7
// 622.178 us; speedup vs baseline: 9.3522x; 1.4218x over previous
//
#include <hip/hip_runtime.h>
#include <math.h>

#define B_ 16
#define J_ 96
#define I_ 96
#define E_ 256
#define H_ 512
#define VS_ 32000
#define SJ_ 193
#define NROW (B_*J_)   // 1536

typedef __attribute__((ext_vector_type(8))) short short8;
typedef __attribute__((ext_vector_type(4))) float f32x4;
typedef __attribute__((ext_vector_type(4))) unsigned int u32x4;

__device__ __forceinline__ float sigf(float x){ return 1.f/(1.f+__expf(-x)); }

__device__ __forceinline__ unsigned short f2bf(float x){
  unsigned int u = __float_as_uint(x);
  unsigned int r = (u + 0x7FFFu + ((u>>16)&1u)) >> 16;
  return (unsigned short)r;
}

#define ASYNC16(gp, lp) __builtin_amdgcn_global_load_lds( \
    (const __attribute__((address_space(1))) unsigned int*)(gp), \
    (__attribute__((address_space(3))) unsigned int*)(lp), 16, 0, 0)

// zero h-exchange (16384 u32) + flags (128 u32) contiguous, and rowsum/nullsum
__global__ void k_init(unsigned int* __restrict__ hexflags, float* __restrict__ rowsum){
  int i = blockIdx.x*256 + threadIdx.x;
  if (i < 16384 + 128) hexflags[i] = 0u;
  if (i < NROW + 1) rowsum[i] = 0.f;
}

// e_word in bf16 only (feeds MFMA projection)
__global__ void k_embed(const int* __restrict__ targets, const float* __restrict__ emb,
                        unsigned short* __restrict__ e_word_h){
  int row = blockIdx.x;
  int t = targets[row];
  e_word_h[(long long)row*E_ + threadIdx.x] = f2bf(emb[(long long)t*E_ + threadIdx.x]);
}

// transpose+convert: src fp32 [K][N] (ld=N) -> dst bf16 [N][K].  512 thr, 64x64 tile.
__device__ __forceinline__ void wtr_tile(const float* __restrict__ src,
                                         unsigned short* __restrict__ dst,
                                         int ldN, int K, int n0, int k0,
                                         float* __restrict__ tile /*[64][65]*/)
{
  const int t = threadIdx.x;
  #pragma unroll
  for (int rep = 0; rep < 8; rep++){
    int idx = rep*512 + t;
    int kk = idx >> 6, nn = idx & 63;
    tile[kk*65 + nn] = src[(long long)(k0+kk)*ldN + n0 + nn];
  }
  __syncthreads();
  #pragma unroll
  for (int rep = 0; rep < 8; rep++){
    int idx = rep*512 + t;
    int nn = idx >> 6, kk = idx & 63;
    dst[(long long)(n0+nn)*K + k0 + kk] = f2bf(tile[kk*65 + nn]);
  }
}

// standalone transposes for Wfw/Wbw (first E_ rows): [256][2048] -> [2048][256] bf16
__global__ __launch_bounds__(512, 2) void k_wtr2(const float* __restrict__ Wfw,
                                                 const float* __restrict__ Wbw,
                                                 unsigned short* __restrict__ WT /*2x 2048*256*/){
  __shared__ float tile[64*65];
  int y = blockIdx.y;
  const float* src = y ? Wbw : Wfw;
  unsigned short* dst = WT + (long long)y*2048*256;
  int sid = blockIdx.x;               // 32 x 4 = 128 tiles
  int n0 = (sid & 31)*64, k0 = (sid >> 5)*64;
  wtr_tile(src, dst, 2048, 256, n0, k0, tile);
}

// ---------------------------------------------------------------------------
// Generic bf16 MFMA GEMM, A [M][K] bf16 rows, B [N][K] bf16 rows (BT layout).
// 128x128 tile, 256 thr, MT = 12 M-tiles (M=1536 always).
// MODE 0: Cf = acc + bias        (fp32)
// MODE 1: Ch = bf16(acc)         (no bias)
// MODE 2: v = tanh(acc+bias); Cf = v; Ch = bf16(v)
// MODE 3: rowsum[m] += sum_col exp(acc + bias)   (no C)
// ---------------------------------------------------------------------------
template<int MODE>
__global__ __launch_bounds__(256, 2) void k_bgemm(
    const unsigned short* __restrict__ Ah,
    const unsigned short* __restrict__ Bh,
    int K,
    const float* __restrict__ bias,
    float* __restrict__ Cf,
    unsigned short* __restrict__ Ch,
    int ldc,
    float* __restrict__ rowsum)
{
  __shared__ unsigned short As[128*32];
  __shared__ unsigned short Bs[128*32];
  // bijective XCD swizzle (nwg divisible by 8 in all uses)
  int nwg = gridDim.x;
  int braw = blockIdx.x;
  int wg = (braw & 7)*(nwg >> 3) + (braw >> 3);
  int mt = wg % 12, nt = wg / 12;
  const int m0 = mt*128, n0 = nt*128;
  const int t = threadIdx.x;
  const int lane = t & 63, w = t >> 6;
  const int wm = (w >> 1)*64, wn = (w & 1)*64;
  f32x4 acc[4][4] = {};
  for (int k0 = 0; k0 < K; k0 += 32){
    #pragma unroll
    for (int p = 0; p < 2; p++){
      int rowA = p*64 + (t >> 2);
      int kc = (t & 3) ^ ((rowA >> 1) & 3);
      const unsigned short* ga = Ah + (long long)(m0 + rowA)*K + k0 + kc*8;
      const unsigned short* gb = Bh + (long long)(n0 + rowA)*K + k0 + kc*8;
      unsigned short* la = As + p*2048 + w*512;
      unsigned short* lb = Bs + p*2048 + w*512;
      ASYNC16(ga, la);
      ASYNC16(gb, lb);
    }
    __syncthreads();
    short8 af[4], bf[4];
    const int rr = lane & 15, kch = lane >> 4;
    #pragma unroll
    for (int mi = 0; mi < 4; mi++){
      int rowA = wm + mi*16 + rr;
      int slot = kch ^ ((rowA >> 1) & 3);
      af[mi] = *(const short8*)&As[rowA*32 + slot*8];
    }
    #pragma unroll
    for (int ni = 0; ni < 4; ni++){
      int rowB = wn + ni*16 + rr;
      int slot = kch ^ ((rowB >> 1) & 3);
      bf[ni] = *(const short8*)&Bs[rowB*32 + slot*8];
    }
    #pragma unroll
    for (int mi = 0; mi < 4; mi++)
      #pragma unroll
      for (int ni = 0; ni < 4; ni++)
        acc[mi][ni] = __builtin_amdgcn_mfma_f32_16x16x32_bf16(af[mi], bf[ni], acc[mi][ni], 0, 0, 0);
    __syncthreads();
  }
  #pragma unroll
  for (int mi = 0; mi < 4; mi++){
    #pragma unroll
    for (int r = 0; r < 4; r++){
      int row = m0 + wm + mi*16 + ((lane >> 4) << 2) + r;
      if (MODE == 3){
        float s = 0.f;
        #pragma unroll
        for (int ni = 0; ni < 4; ni++){
          int col = n0 + wn + ni*16 + (lane & 15);
          s += __expf(acc[mi][ni][r] + bias[col]);
        }
        s += __shfl_xor(s, 1);
        s += __shfl_xor(s, 2);
        s += __shfl_xor(s, 4);
        s += __shfl_xor(s, 8);
        if ((lane & 15) == 0) atomicAdd(&rowsum[row], s);
      } else {
        #pragma unroll
        for (int ni = 0; ni < 4; ni++){
          int col = n0 + wn + ni*16 + (lane & 15);
          float v = acc[mi][ni][r];
          if (MODE == 0){ Cf[(long long)row*ldc + col] = v + bias[col]; }
          if (MODE == 1){ Ch[(long long)row*ldc + col] = f2bf(v); }
          if (MODE == 2){
            v = tanhf(v + bias[col]);
            Cf[(long long)row*ldc + col] = v;
            Ch[(long long)row*ldc + col] = f2bf(v);
          }
        }
      }
    }
  }
}

// ---------------------------------------------------------------------------
// Fused persistent bi-LSTM + hidden side work.
// Blocks 0..63: LSTM, 32 blocks/dir, 16 hidden units (64 gate cols) each.
//   512 thr = 8 waves = 8 K-eighths; r4-proven flag protocol, 2 barriers/step.
// Blocks 64+: side tasks (input-only, no waits -> deadlock-free any order):
//   tnp0 (1), Wv->WvT bf16 transpose (4000), nullrow (63, recomputes tn),
//   Wl->WlT (64), W1->W1T (32).   Grid total 4224.
// hex: [dir][par][16 batch][512 h bf16] (16 KB/par).  flags: [dir][32].
// ---------------------------------------------------------------------------
__global__ __launch_bounds__(512, 1) void k_fused(
    const float* __restrict__ Xfw, const float* __restrict__ Xbw,
    const float* __restrict__ Wfw, const float* __restrict__ Wbw,
    unsigned int* __restrict__ hex32,
    unsigned int* __restrict__ flags,
    unsigned short* __restrict__ Hcat_h,
    // side-task args
    const int* __restrict__ tnull, const float* __restrict__ emb,
    const float* __restrict__ W1, const float* __restrict__ b1,
    const float* __restrict__ Wp, const float* __restrict__ bp,
    const float* __restrict__ Wv, const float* __restrict__ bv,
    unsigned short* __restrict__ WvT,
    float* __restrict__ lognull, float* __restrict__ nullsum,
    float* __restrict__ p0,
    const float* __restrict__ Wl, unsigned short* __restrict__ WlT,
    unsigned short* __restrict__ W1T)
{
  __shared__ __align__(16) unsigned short W_s[64*512];   // 64 KB
  __shared__ __align__(16) float z_s[8][16][68];         // 34.8 KB
  const int bid = blockIdx.x;
  const int t = threadIdx.x;                 // 0..511

  if (bid >= 64){
    // ---------------- side tasks ----------------
    float* zflat = &z_s[0][0][0];
    int sid = bid - 64;
    if (sid == 0){
      // tnp0: p0 = sigmoid( tanh(e_null@W1+b1) . Wp + bp ) * 0.3
      float* en  = zflat;            // [256]
      float* red = zflat + 256;      // [512]
      if (t < E_) en[t] = emb[(long long)tnull[0]*E_ + t];
      __syncthreads();
      float s = b1[t];
      for (int e = 0; e < E_; e++) s += en[e]*W1[(long long)e*H_ + t];
      red[t] = tanhf(s)*Wp[t];
      __syncthreads();
      for (int w = 256; w > 0; w >>= 1){
        if (t < w) red[t] += red[t+w];
        __syncthreads();
      }
      if (t == 0) p0[0] = sigf(red[0] + bp[0])*0.3f;
      return;
    }
    sid -= 1;
    if (sid < 4000){   // Wv [512][32000] -> WvT [32000][512] bf16
      wtr_tile(Wv, WvT, VS_, H_, (sid % 500)*64, (sid / 500)*64, zflat);
      return;
    }
    sid -= 4000;
    if (sid < 63){     // nullrow: lognull + nullsum (recomputes tn locally)
      float* en  = zflat;            // [256]
      float* tns = zflat + 256;      // [512]
      float* red = zflat + 768;      // [512]
      if (t < E_) en[t] = emb[(long long)tnull[0]*E_ + t];
      __syncthreads();
      float s0 = b1[t];
      for (int e = 0; e < E_; e++) s0 += en[e]*W1[(long long)e*H_ + t];
      tns[t] = tanhf(s0);
      __syncthreads();
      int c = sid*512 + t;
      float p = 0.f;
      if (c < VS_){
        float s = bv[c];
        for (int k = 0; k < H_; k++) s += tns[k]*Wv[(long long)k*VS_ + c];
        lognull[c] = s;
        p = __expf(s);
      }
      red[t] = p;
      __syncthreads();
      for (int w = 256; w > 0; w >>= 1){
        if (t < w) red[t] += red[t+w];
        __syncthreads();
      }
      if (t == 0) atomicAdd(nullsum, red[0]);
      return;
    }
    sid -= 63;
    if (sid < 64){     // Wl [1024][256] -> WlT [256][1024] bf16
      wtr_tile(Wl, WlT, 256, 1024, (sid & 3)*64, (sid >> 2)*64, zflat);
      return;
    }
    sid -= 64;
    // W1 [256][512] -> W1T [512][256] bf16   (32 tiles)
    wtr_tile(W1, W1T, 512, 256, (sid & 7)*64, (sid >> 3)*64, zflat);
    return;
  }

  // ---------------- LSTM path ----------------
  const int dir = bid >> 5;
  const int slice = bid & 31;
  const int u0 = slice * 16;                 // 16 hidden units per block
  const int lane = t & 63;
  const int w = t >> 6;                      // wave = K-eighth
  const int m = lane & 15, hi = lane >> 4;
  const float* X = dir ? Xbw : Xfw;
  const float* Wg = (dir ? Wbw : Wfw) + (long long)E_*2048;
  char* hexd = (char*)hex32 + dir*32768;     // per-dir: 2 par x 16 KB
  unsigned int* flg = flags + dir*32;

  // stage W slice -> LDS bf16 [col(64)][k(512)], 16B-block XOR swizzle
  for (int rep = 0; rep < 8; rep++){
    int id = rep*512 + t;                    // 0..4095
    int k = id >> 3, col8 = (id & 7)*8;
    int g = col8 >> 4, uu0 = col8 & 15;
    const float* src = Wg + (long long)k*2048 + g*512 + u0 + uu0;
    float4 w0 = *(const float4*)src;
    float4 w1 = *(const float4*)(src + 4);
    float wv8[8] = {w0.x,w0.y,w0.z,w0.w,w1.x,w1.y,w1.z,w1.w};
    #pragma unroll
    for (int j = 0; j < 8; j++){
      int c = col8 + j;
      int byte = (c << 10) + (k << 1);
      byte ^= ((c & 7) << 4);
      *(unsigned short*)((char*)W_s + byte) = f2bf(wv8[j]);
    }
  }
  __syncthreads();

  // hoist B-fragments: wave w covers chunks kc = 2w, 2w+1; cols nt*16+m
  short8 bfr[4][2];
  #pragma unroll
  for (int nt = 0; nt < 4; nt++)
    #pragma unroll
    for (int ck = 0; ck < 2; ck++){
      int col = nt*16 + m;
      int kc = 2*w + ck;
      int byte = (col << 10) + kc*64 + hi*16;
      byte ^= ((col & 7) << 4);
      bfr[nt][ck] = *(const short8*)((const char*)W_s + byte);
    }

  // gate threads: t<256, eb = t>>4 (batch), eu = t&15 (unit)
  const int eb = t >> 4, eu = t & 15;
  float creg = 0.f;

  for (int step = 0; step < J_; step++){
    const int par = step & 1;
    const int t_eff = dir ? (J_-1-step) : step;
    // X prefetch BEFORE poll (latency hides under the spin)
    float xg0=0.f, xg1=0.f, xg2=0.f, xg3=0.f;
    if (t < 256){
      const float* xr = X + ((long long)eb*J_ + t_eff)*2048 + u0 + eu;
      xg0 = xr[0]; xg1 = xr[512]; xg2 = xr[1024]; xg3 = xr[1536];
    }
    if (step > 0){
      for (;;){
        unsigned int v = __hip_atomic_load(&flg[lane & 31], __ATOMIC_RELAXED,
                                           __HIP_MEMORY_SCOPE_AGENT);
        if (__all((int)(v >= (unsigned)step))) break;
        __builtin_amdgcn_s_sleep(1);
      }
    }
    __builtin_amdgcn_sched_barrier(0);
    // A-fragment loads: 2x16B per lane, from coherence point
    const char* ap = hexd + par*16384 + m*1024 + w*128 + hi*16;
    u32x4 d0, d1;
    asm volatile("global_load_dwordx4 %0, %1, off sc0 sc1" : "=v"(d0) : "v"(ap));
    asm volatile("global_load_dwordx4 %0, %1, off offset:64 sc0 sc1" : "=v"(d1) : "v"(ap));
    asm volatile("s_waitcnt vmcnt(0)" ::: "memory");
    __builtin_amdgcn_sched_barrier(0);
    union { u32x4 u; short8 s; } a0, a1;
    a0.u = d0; a1.u = d1;
    f32x4 acc[4] = {{0.f,0.f,0.f,0.f},{0.f,0.f,0.f,0.f},{0.f,0.f,0.f,0.f},{0.f,0.f,0.f,0.f}};
    #pragma unroll
    for (int nt = 0; nt < 4; nt++){
      acc[nt] = __builtin_amdgcn_mfma_f32_16x16x32_bf16(a0.s, bfr[nt][0], acc[nt], 0,0,0);
      acc[nt] = __builtin_amdgcn_mfma_f32_16x16x32_bf16(a1.s, bfr[nt][1], acc[nt], 0,0,0);
    }
    #pragma unroll
    for (int nt = 0; nt < 4; nt++)
      #pragma unroll
      for (int r = 0; r < 4; r++)
        z_s[w][hi*4 + r][nt*16 + m] = acc[nt][r];
    __syncthreads();
    if (t < 256){
      float z0 = xg0, z1 = xg1, z2 = xg2, z3 = xg3;
      #pragma unroll
      for (int ke = 0; ke < 8; ke++){
        z0 += z_s[ke][eb][eu];
        z1 += z_s[ke][eb][16 + eu];
        z2 += z_s[ke][eb][32 + eu];
        z3 += z_s[ke][eb][48 + eu];
      }
      creg = sigf(z2 + 1.f)*creg + sigf(z0)*tanhf(z1);
      float hh = sigf(z3)*tanhf(creg);
      unsigned int hb16 = (unsigned int)f2bf(hh);
      unsigned int nb = (unsigned int)__shfl_xor((int)hb16, 1);
      if (!(eu & 1))
        __hip_atomic_store((unsigned int*)(hexd + (par^1)*16384 + eb*1024 + (u0 + eu)*2),
                           (hb16 & 0xffffu) | (nb << 16),
                           __ATOMIC_RELAXED, __HIP_MEMORY_SCOPE_AGENT);
      Hcat_h[((long long)eb*J_ + t_eff)*1024 + dir*512 + u0 + eu] = (unsigned short)hb16;
    }
    __syncthreads();   // drains all waves' vmcnt -> h stores at coherence point
    if (t == 0)
      __hip_atomic_store(&flg[slice], (unsigned int)(step+1),
                         __ATOMIC_RELAXED, __HIP_MEMORY_SCOPE_AGENT);
  }
}

// Generic 64x64 tiled fp32 GEMM (kept for jump logits only)
template<int EPI>
__global__ void k_gemm(const float* __restrict__ A, int lda,
                       const float* __restrict__ B, int ldb,
                       float* __restrict__ C, int ldc,
                       int M, int N, int K,
                       const float* __restrict__ bias)
{
  const int m0 = blockIdx.y*64, n0 = blockIdx.x*64;
  __shared__ float As[16][68];
  __shared__ float Bs[16][68];
  const int tid = threadIdx.x;         // 256
  const int tx = tid & 15, ty = tid >> 4;
  float acc[4][4] = {};
  for (int k0 = 0; k0 < K; k0 += 16){
    {
      const int kk = tid & 15, r0 = tid >> 4;
      #pragma unroll
      for (int i = 0; i < 4; i++){
        int rr = r0 + i*16, mm = m0 + rr;
        As[kk][rr] = (mm < M) ? A[(long long)mm*lda + k0 + kk] : 0.f;
      }
    }
    {
      const int c = tid & 63, k4 = tid >> 6;
      #pragma unroll
      for (int i = 0; i < 4; i++){
        int kk = k4 + i*4, n = n0 + c;
        Bs[kk][c] = (n < N) ? B[(long long)(k0+kk)*ldb + n] : 0.f;
      }
    }
    __syncthreads();
    #pragma unroll
    for (int kk = 0; kk < 16; kk++){
      float a[4], b[4];
      #pragma unroll
      for (int i = 0; i < 4; i++) a[i] = As[kk][ty*4 + i];
      #pragma unroll
      for (int j = 0; j < 4; j++) b[j] = Bs[kk][tx*4 + j];
      #pragma unroll
      for (int i = 0; i < 4; i++)
        #pragma unroll
        for (int j = 0; j < 4; j++)
          acc[i][j] += a[i]*b[j];
    }
    __syncthreads();
  }
  #pragma unroll
  for (int i = 0; i < 4; i++){
    int mm = m0 + ty*4 + i;
    if (mm >= M) continue;
    #pragma unroll
    for (int j = 0; j < 4; j++){
      int n = n0 + tx*4 + j;
      if (n >= N) continue;
      C[(long long)mm*ldc + n] = acc[i][j] + (bias ? bias[n] : 0.f);
    }
  }
}

// gathered-logits GEMM + word-emission epilogue. One block per batch.
__global__ __launch_bounds__(256, 2) void k_glgemm(
    const unsigned short* __restrict__ t1h,   // [1536][512]
    const unsigned short* __restrict__ WvT,   // [32000][512]
    const float* __restrict__ bv,
    const int* __restrict__ sources,          // [16][96]
    const float* __restrict__ rowsum,         // [1536]
    float* __restrict__ out_em)               // [16][192][96]
{
  __shared__ int   srcs[96];
  __shared__ float bgs[96];
  const int b = blockIdx.x;
  const int t = threadIdx.x, lane = t & 63, w = t >> 6;
  if (t < 96){ int s = sources[b*96 + t]; srcs[t] = s; bgs[t] = bv[s]; }
  __syncthreads();
  const int rr = lane & 15, kq = lane >> 4;
  for (int tile = w; tile < 36; tile += 4){
    int mt = tile / 6, nt = tile % 6;
    const unsigned short* arow = t1h + ((long long)(b*96 + mt*16 + rr))*512 + kq*8;
    const unsigned short* brow = WvT + (long long)srcs[nt*16 + rr]*512 + kq*8;
    f32x4 acc = {0.f,0.f,0.f,0.f};
    #pragma unroll
    for (int kc = 0; kc < 16; kc++){
      short8 af = *(const short8*)(arow + kc*32);
      short8 bf = *(const short8*)(brow + kc*32);
      acc = __builtin_amdgcn_mfma_f32_16x16x32_bf16(af, bf, acc, 0, 0, 0);
    }
    #pragma unroll
    for (int r = 0; r < 4; r++){
      int j = mt*16 + kq*4 + r;
      int i = nt*16 + rr;
      float v = __expf(acc[r] + bgs[i]) / rowsum[b*96 + j];
      out_em[((long long)b*192 + j)*96 + i] = v;
    }
  }
}

// null half of emission: 96 identical rows per batch
__global__ void k_emission_null(const float* __restrict__ lognull,
                                const float* __restrict__ nullsum,
                                const int* __restrict__ sources,
                                float* __restrict__ out_em){
  int b = blockIdx.x;
  int i = threadIdx.x;
  if (i >= 96) return;
  int s = sources[b*96 + i];
  float v = __expf(lognull[s]) / nullsum[0];
  for (int jj = 0; jj < 96; jj++)
    out_em[((long long)b*192 + 96 + jj)*96 + i] = v;
}

__global__ void k_transition(const float* __restrict__ jlog, const float* __restrict__ p0p,
                             float* __restrict__ T, float* __restrict__ TL){
  int bx = blockIdx.x;           // b*J_ + j
  int b = bx / J_, j = bx % J_;
  int tid = threadIdx.x;         // 128
  __shared__ float ex[128];
  __shared__ float red[128];
  float e = 0.f;
  if (tid < 96) e = __expf(jlog[(long long)bx*SJ_ + (96 - j + tid)]);
  ex[tid] = e; red[tid] = e;
  __syncthreads();
  for (int w = 64; w > 0; w >>= 1){
    if (tid < w) red[tid] += red[tid+w];
    __syncthreads();
  }
  float p0 = p0p[0];
  float scale = (1.f - p0) / red[0];
  float lp0 = logf(p0);
  long long r0 = ((long long)b*192 + j)*192;
  long long r1 = ((long long)b*192 + j + 96)*192;
  for (int col = tid; col < 192; col += 128){
    float tv, lv;
    if (col < 96){ tv = ex[col]*scale; lv = logf(tv); }
    else { bool d = (col - 96) == j; tv = d ? p0 : 0.f; lv = d ? lp0 : 0.f; }
    T[r0 + col] = tv; T[r1 + col] = tv;
    TL[r0 + col] = lv; TL[r1 + col] = lv;
  }
}

extern "C" void kernel_launch(void* const* d_in, const int* in_sizes, int n_in,
                              void* d_out, int out_size, void* d_ws, size_t ws_size,
                              hipStream_t stream)
{
  const int* sources = (const int*)d_in[0];
  const int* targets = (const int*)d_in[1];
  const int* tnull   = (const int*)d_in[2];
  const float* emb   = (const float*)d_in[3];
  const float* Wfw   = (const float*)d_in[4];
  const float* bfw   = (const float*)d_in[5];
  const float* Wbw   = (const float*)d_in[6];
  const float* bbw   = (const float*)d_in[7];
  const float* Wl    = (const float*)d_in[8];
  const float* W1    = (const float*)d_in[9];
  const float* b1    = (const float*)d_in[10];
  const float* Wv    = (const float*)d_in[11];
  const float* bv    = (const float*)d_in[12];
  const float* Wj    = (const float*)d_in[13];
  const float* bj    = (const float*)d_in[14];
  const float* Wp    = (const float*)d_in[15];
  const float* bp    = (const float*)d_in[16];
  float* out = (float*)d_out;
  float* ws  = (float*)d_ws;

  long long off = 0;
  float* Xfw    = ws + off; off += (long long)NROW*2048;
  float* Xbw    = ws + off; off += (long long)NROW*2048;
  unsigned short* e_word_h = (unsigned short*)(ws + off); off += (long long)NROW*E_/2;
  unsigned short* WT       = (unsigned short*)(ws + off); off += 2LL*2048*256/2;   // WfwT|WbwT
  unsigned short* Hcat_h   = (unsigned short*)(ws + off); off += (long long)NROW*1024/2;
  unsigned int* hex32 = (unsigned int*)(ws + off); off += 16384;  // [2dir][2par][16][512] bf16
  unsigned int* flags = (unsigned int*)(ws + off); off += 128;
  unsigned short* ts_h = (unsigned short*)(ws + off); off += (long long)NROW*E_/2;
  float* t1     = ws + off; off += (long long)NROW*H_;
  unsigned short* t1h = (unsigned short*)(ws + off); off += (long long)NROW*H_/2;
  unsigned short* WlT = (unsigned short*)(ws + off); off += 256LL*1024/2;
  unsigned short* W1T = (unsigned short*)(ws + off); off += 512LL*256/2;
  float* rowsum = ws + off; off += NROW;
  float* nullsum= ws + off; off += 1;
  float* p0     = ws + off; off += 1;
  float* lognull= ws + off; off += VS_;
  float* jlog   = ws + off; off += (long long)NROW*SJ_;
  unsigned short* WvT = (unsigned short*)(ws + off); off += (long long)VS_*H_/2;

  float* out_em = out;
  float* out_T  = out + (long long)B_*192*96;
  float* out_TL = out_T + (long long)B_*192*192;

  // init: h-exchange + flags, rowsum + nullsum
  k_init<<<65, 256, 0, stream>>>(hex32, rowsum);

  k_embed<<<NROW, 256, 0, stream>>>(targets, emb, e_word_h);
  k_wtr2<<<dim3(128, 2), 512, 0, stream>>>(Wfw, Wbw, WT);

  // input projections (bf16 MFMA): X = e_word @ W[:256] + b, fp32 out
  k_bgemm<0><<<192, 256, 0, stream>>>(e_word_h, WT,             E_, bfw, Xfw, nullptr, 2048, nullptr);
  k_bgemm<0><<<192, 256, 0, stream>>>(e_word_h, WT + 2048*256,  E_, bbw, Xbw, nullptr, 2048, nullptr);

  // fused persistent bi-LSTM + side work (WvT, nullrow, tnp0, WlT, W1T)
  k_fused<<<4224, 512, 0, stream>>>(Xfw, Xbw, Wfw, Wbw, hex32, flags, Hcat_h,
                                    tnull, emb, W1, b1, Wp, bp, Wv, bv,
                                    WvT, lognull, nullsum, p0, Wl, WlT, W1T);

  // ts_h = bf16(Hcat @ Wl)   [1536,1024]@[1024,256]
  k_bgemm<1><<<24, 256, 0, stream>>>(Hcat_h, WlT, 2*H_, nullptr, nullptr, ts_h, E_, nullptr);
  // t1 = tanh(ts @ W1 + b1)  [1536,256]@[256,512] -> fp32 + bf16
  k_bgemm<2><<<48, 256, 0, stream>>>(ts_h, W1T, E_, b1, t1, t1h, H_, nullptr);

  // jump logits (fp32): [1536,512]@[512,193] + bj
  k_gemm<0><<<dim3(4, NROW/64), 256, 0, stream>>>(t1, H_, Wj, SJ_, jlog, SJ_,
                                                  NROW, SJ_, H_, bj);

  // rowsum[m] = sum_n exp(logits) via bf16 MFMA GEMM
  k_bgemm<3><<<3000, 256, 0, stream>>>(t1h, WvT, H_, bv, nullptr, nullptr, VS_, rowsum);

  // gathered logits + word emission (fused)
  k_glgemm<<<B_, 256, 0, stream>>>(t1h, WvT, bv, sources, rowsum, out_em);

  k_emission_null<<<B_, 128, 0, stream>>>(lognull, nullsum, sources, out_em);
  k_transition<<<NROW, 128, 0, stream>>>(jlog, p0, out_T, out_TL);
}

// Round 8
// 483.537 us; speedup vs baseline: 12.0337x; 1.2867x over previous
//
#include <hip/hip_runtime.h>
#include <math.h>

#define B_ 16
#define J_ 96
#define I_ 96
#define E_ 256
#define H_ 512
#define VS_ 32000
#define SJ_ 193
#define NROW (B_*J_)   // 1536

typedef __attribute__((ext_vector_type(8))) short short8;
typedef __attribute__((ext_vector_type(4))) float f32x4;
typedef __attribute__((ext_vector_type(4))) unsigned int u32x4;

__device__ __forceinline__ float sigf(float x){ return 1.f/(1.f+__expf(-x)); }

__device__ __forceinline__ unsigned short f2bf(float x){
  unsigned int u = __float_as_uint(x);
  unsigned int r = (u + 0x7FFFu + ((u>>16)&1u)) >> 16;
  return (unsigned short)r;
}

#define ASYNC16(gp, lp) __builtin_amdgcn_global_load_lds( \
    (const __attribute__((address_space(1))) unsigned int*)(gp), \
    (__attribute__((address_space(3))) unsigned int*)(lp), 16, 0, 0)

// zero tagged h-exchange (32768 u32 = 128 KB) + rowsum/nullsum
__global__ void k_init(unsigned int* __restrict__ hex, float* __restrict__ rowsum){
  int i = blockIdx.x*256 + threadIdx.x;
  if (i < 32768) hex[i] = 0u;
  if (i < NROW + 1) rowsum[i] = 0.f;
}

// e_word in bf16 (feeds MFMA projection)
__global__ void k_embed(const int* __restrict__ targets, const float* __restrict__ emb,
                        unsigned short* __restrict__ e_word_h){
  int row = blockIdx.x;
  int t = targets[row];
  e_word_h[(long long)row*E_ + threadIdx.x] = f2bf(emb[(long long)t*E_ + threadIdx.x]);
}

// transpose+convert: src fp32 [K][nmax] (ld=ldN) -> dst bf16 [N][K], zero pad n>=nmax.
__device__ __forceinline__ void wtr_tile(const float* __restrict__ src,
                                         unsigned short* __restrict__ dst,
                                         int ldN, int nmax, int K, int n0, int k0,
                                         float* __restrict__ tile /*[64][65]*/)
{
  const int t = threadIdx.x;
  #pragma unroll
  for (int rep = 0; rep < 8; rep++){
    int idx = rep*512 + t;
    int kk = idx >> 6, nn = idx & 63;
    tile[kk*65 + nn] = (n0+nn < nmax) ? src[(long long)(k0+kk)*ldN + n0 + nn] : 0.f;
  }
  __syncthreads();
  #pragma unroll
  for (int rep = 0; rep < 8; rep++){
    int idx = rep*512 + t;
    int nn = idx >> 6, kk = idx & 63;
    dst[(long long)(n0+nn)*K + k0 + kk] = f2bf(tile[kk*65 + nn]);
  }
}

// transposes for Wfw/Wbw (first E_ rows): [256][2048] -> [2048][256] bf16
__global__ __launch_bounds__(512, 2) void k_wtr2(const float* __restrict__ Wfw,
                                                 const float* __restrict__ Wbw,
                                                 unsigned short* __restrict__ WT){
  __shared__ float tile[64*65];
  int y = blockIdx.y;
  const float* src = y ? Wbw : Wfw;
  unsigned short* dst = WT + (long long)y*2048*256;
  int sid = blockIdx.x;               // 32 x 4 = 128 tiles
  int n0 = (sid & 31)*64, k0 = (sid >> 5)*64;
  wtr_tile(src, dst, 2048, 2048, 256, n0, k0, tile);
}

// ---------------------------------------------------------------------------
// Generic bf16 MFMA GEMM, A [M][K] bf16 rows, B [N][K] bf16 rows (BT layout).
// 128x128 tile, 256 thr, 12 M-tiles (M=1536). grid = 12 * ntN (ntN = N-tiles).
// MODE 0: Cf = acc + bias (fp32, col<ncols guarded)
// MODE 2: Ch = bf16(tanh(acc+bias)); Cf optional
// MODE 3: rowsum[m] += sum_col exp(acc + bias)
// ---------------------------------------------------------------------------
template<int MODE>
__global__ __launch_bounds__(256, 2) void k_bgemm(
    const unsigned short* __restrict__ Ah,
    const unsigned short* __restrict__ Bh,
    int K, int ncols,
    const float* __restrict__ bias,
    float* __restrict__ Cf,
    unsigned short* __restrict__ Ch,
    int ldc,
    float* __restrict__ rowsum)
{
  __shared__ unsigned short As[128*32];
  __shared__ unsigned short Bs[128*32];
  int nwg = gridDim.x;
  int braw = blockIdx.x;
  int wg = (braw & 7)*(nwg >> 3) + (braw >> 3);   // bijective: nwg % 8 == 0
  int mt = wg % 12, nt = wg / 12;
  const int m0 = mt*128, n0 = nt*128;
  const int t = threadIdx.x;
  const int lane = t & 63, w = t >> 6;
  const int wm = (w >> 1)*64, wn = (w & 1)*64;
  f32x4 acc[4][4] = {};
  for (int k0 = 0; k0 < K; k0 += 32){
    #pragma unroll
    for (int p = 0; p < 2; p++){
      int rowA = p*64 + (t >> 2);
      int kc = (t & 3) ^ ((rowA >> 1) & 3);
      const unsigned short* ga = Ah + (long long)(m0 + rowA)*K + k0 + kc*8;
      const unsigned short* gb = Bh + (long long)(n0 + rowA)*K + k0 + kc*8;
      unsigned short* la = As + p*2048 + w*512;
      unsigned short* lb = Bs + p*2048 + w*512;
      ASYNC16(ga, la);
      ASYNC16(gb, lb);
    }
    __syncthreads();
    short8 af[4], bf[4];
    const int rr = lane & 15, kch = lane >> 4;
    #pragma unroll
    for (int mi = 0; mi < 4; mi++){
      int rowA = wm + mi*16 + rr;
      int slot = kch ^ ((rowA >> 1) & 3);
      af[mi] = *(const short8*)&As[rowA*32 + slot*8];
    }
    #pragma unroll
    for (int ni = 0; ni < 4; ni++){
      int rowB = wn + ni*16 + rr;
      int slot = kch ^ ((rowB >> 1) & 3);
      bf[ni] = *(const short8*)&Bs[rowB*32 + slot*8];
    }
    #pragma unroll
    for (int mi = 0; mi < 4; mi++)
      #pragma unroll
      for (int ni = 0; ni < 4; ni++)
        acc[mi][ni] = __builtin_amdgcn_mfma_f32_16x16x32_bf16(af[mi], bf[ni], acc[mi][ni], 0, 0, 0);
    __syncthreads();
  }
  #pragma unroll
  for (int mi = 0; mi < 4; mi++){
    #pragma unroll
    for (int r = 0; r < 4; r++){
      int row = m0 + wm + mi*16 + ((lane >> 4) << 2) + r;
      if (MODE == 3){
        float s = 0.f;
        #pragma unroll
        for (int ni = 0; ni < 4; ni++){
          int col = n0 + wn + ni*16 + (lane & 15);
          s += __expf(acc[mi][ni][r] + bias[col]);
        }
        s += __shfl_xor(s, 1);
        s += __shfl_xor(s, 2);
        s += __shfl_xor(s, 4);
        s += __shfl_xor(s, 8);
        if ((lane & 15) == 0) atomicAdd(&rowsum[row], s);
      } else {
        #pragma unroll
        for (int ni = 0; ni < 4; ni++){
          int col = n0 + wn + ni*16 + (lane & 15);
          if (col >= ncols) continue;
          float v = acc[mi][ni][r] + (bias ? bias[col] : 0.f);
          if (MODE == 0){ Cf[(long long)row*ldc + col] = v; }
          if (MODE == 2){
            v = tanhf(v);
            if (Cf) Cf[(long long)row*ldc + col] = v;
            Ch[(long long)row*ldc + col] = f2bf(v);
          }
        }
      }
    }
  }
}

// ---------------------------------------------------------------------------
// Fused persistent bi-LSTM (tagged packets) + hidden side work.
// Blocks 0..63: LSTM, 32 blocks/dir, 16 hidden units (64 gate cols) each.
//   512 thr = 8 waves = 8 K-eighths. Packet = u64 {bf16 h[2u], h[2u+1], tag}.
//   Producer (step s): one __hip_atomic_store<u64> per h-pair, tag = s+1, into
//   parity (s+1)&1. Consumer (step s): polls ITS OWN A-frag packets in parity
//   s&1 for tag == s (zero-init => tag 0 valid for step 0). No flags, no
//   drains, ONE barrier/step; z_s parity-double-buffered (overwrite safety via
//   tag chain: any poll(s+2) success implies all step-s z reads done).
// Blocks 64+: side tasks (input-only, deadlock-free): tnp0(1), W_comboT(128),
//   WjT(32), nullrow(63), WvT(4000). hex: [dir][par][16 batch][256 pkt u64].
// ---------------------------------------------------------------------------
__global__ __launch_bounds__(512, 1) void k_fused(
    const float* __restrict__ Xfw, const float* __restrict__ Xbw,
    const float* __restrict__ Wfw, const float* __restrict__ Wbw,
    unsigned int* __restrict__ hex32,
    unsigned short* __restrict__ Hcat_h,
    // side-task args
    const int* __restrict__ tnull, const float* __restrict__ emb,
    const float* __restrict__ W1, const float* __restrict__ b1,
    const float* __restrict__ Wp, const float* __restrict__ bp,
    const float* __restrict__ Wv, const float* __restrict__ bv,
    unsigned short* __restrict__ WvT,
    float* __restrict__ lognull, float* __restrict__ nullsum,
    float* __restrict__ p0,
    const float* __restrict__ Wl, unsigned short* __restrict__ W_comboT,
    const float* __restrict__ Wj, unsigned short* __restrict__ WjT)
{
  __shared__ __align__(16) unsigned short W_s[64*512];   // 64 KB
  __shared__ __align__(16) float z_s[2][8][16][68];      // 69.6 KB parity-dbuf
  const int bid = blockIdx.x;
  const int t = threadIdx.x;                 // 0..511

  if (bid >= 64){
    // ---------------- side tasks ----------------
    float* zflat = &z_s[0][0][0][0];
    int sid = bid - 64;
    if (sid == 0){
      float* en  = zflat;            // [256]
      float* red = zflat + 256;      // [512]
      if (t < E_) en[t] = emb[(long long)tnull[0]*E_ + t];
      __syncthreads();
      float s = b1[t];
      for (int e = 0; e < E_; e++) s += en[e]*W1[(long long)e*H_ + t];
      red[t] = tanhf(s)*Wp[t];
      __syncthreads();
      for (int w = 256; w > 0; w >>= 1){
        if (t < w) red[t] += red[t+w];
        __syncthreads();
      }
      if (t == 0) p0[0] = sigf(red[0] + bp[0])*0.3f;
      return;
    }
    sid -= 1;
    if (sid < 128){
      // W_comboT[n][k] = sum_e Wl[k][e] * W1[e][n], k-strip of 8 rows
      const int K8 = sid*8;
      float* WlS = zflat;            // [8][256]
      #pragma unroll
      for (int rep = 0; rep < 4; rep++){
        int id = rep*512 + t;        // 0..2047
        int kl = id >> 8, e = id & 255;
        WlS[kl*256 + e] = Wl[(long long)(K8 + kl)*256 + e];
      }
      __syncthreads();
      float acc[8] = {};
      for (int e = 0; e < 256; e++){
        float w1v = W1[(long long)e*512 + t];
        #pragma unroll
        for (int j = 0; j < 8; j++) acc[j] += WlS[j*256 + e]*w1v;
      }
      #pragma unroll
      for (int j = 0; j < 8; j++)
        W_comboT[(long long)t*1024 + K8 + j] = f2bf(acc[j]);
      return;
    }
    sid -= 128;
    if (sid < 32){   // Wj [512][193] -> WjT [256(pad)][512] bf16
      wtr_tile(Wj, WjT, SJ_, SJ_, 512, (sid & 3)*64, (sid >> 2)*64, zflat);
      return;
    }
    sid -= 32;
    if (sid < 63){   // nullrow (recomputes tn locally)
      float* en  = zflat;
      float* tns = zflat + 256;
      float* red = zflat + 768;
      if (t < E_) en[t] = emb[(long long)tnull[0]*E_ + t];
      __syncthreads();
      float s0 = b1[t];
      for (int e = 0; e < E_; e++) s0 += en[e]*W1[(long long)e*H_ + t];
      tns[t] = tanhf(s0);
      __syncthreads();
      int c = sid*512 + t;
      float p = 0.f;
      if (c < VS_){
        float s = bv[c];
        for (int k = 0; k < H_; k++) s += tns[k]*Wv[(long long)k*VS_ + c];
        lognull[c] = s;
        p = __expf(s);
      }
      red[t] = p;
      __syncthreads();
      for (int w = 256; w > 0; w >>= 1){
        if (t < w) red[t] += red[t+w];
        __syncthreads();
      }
      if (t == 0) atomicAdd(nullsum, red[0]);
      return;
    }
    sid -= 63;
    // Wv [512][32000] -> WvT [32000][512] bf16   (4000 tiles)
    wtr_tile(Wv, WvT, VS_, VS_, H_, (sid % 500)*64, (sid / 500)*64, zflat);
    return;
  }

  // ---------------- LSTM path ----------------
  const int dir = bid >> 5;
  const int slice = bid & 31;
  const int u0 = slice * 16;                 // 16 hidden units per block
  const int lane = t & 63;
  const int w = t >> 6;                      // wave = K-eighth
  const int m = lane & 15, hi = lane >> 4;
  const float* X = dir ? Xbw : Xfw;
  const float* Wg = (dir ? Wbw : Wfw) + (long long)E_*2048;
  char* hexd = (char*)hex32 + dir*65536;     // per-dir: 2 par x 32 KB

  // stage W slice -> LDS bf16 [col(64)][k(512)], 16B-block XOR swizzle
  for (int rep = 0; rep < 8; rep++){
    int id = rep*512 + t;                    // 0..4095
    int k = id >> 3, col8 = (id & 7)*8;
    int g = col8 >> 4, uu0 = col8 & 15;
    const float* src = Wg + (long long)k*2048 + g*512 + u0 + uu0;
    float4 w0 = *(const float4*)src;
    float4 w1 = *(const float4*)(src + 4);
    float wv8[8] = {w0.x,w0.y,w0.z,w0.w,w1.x,w1.y,w1.z,w1.w};
    #pragma unroll
    for (int j = 0; j < 8; j++){
      int c = col8 + j;
      int byte = (c << 10) + (k << 1);
      byte ^= ((c & 7) << 4);
      *(unsigned short*)((char*)W_s + byte) = f2bf(wv8[j]);
    }
  }
  __syncthreads();

  // hoist B-fragments: wave w covers chunks kc = 2w, 2w+1; cols nt*16+m
  short8 bfr[4][2];
  #pragma unroll
  for (int nt = 0; nt < 4; nt++)
    #pragma unroll
    for (int ck = 0; ck < 2; ck++){
      int col = nt*16 + m;
      int kc = 2*w + ck;
      int byte = (col << 10) + kc*64 + hi*16;
      byte ^= ((col & 7) << 4);
      bfr[nt][ck] = *(const short8*)((const char*)W_s + byte);
    }

  // gate threads: t<256, eb = t>>4 (batch), eu = t&15 (unit)
  const int eb = t >> 4, eu = t & 15;
  float creg = 0.f;

  for (int step = 0; step < J_; step++){
    const int par = step & 1;
    const int t_eff = dir ? (J_-1-step) : step;
    // X prefetch BEFORE poll (latency hides under the spin)
    float xg0=0.f, xg1=0.f, xg2=0.f, xg3=0.f;
    if (t < 256){
      const float* xr = X + ((long long)eb*J_ + t_eff)*2048 + u0 + eu;
      xg0 = xr[0]; xg1 = xr[512]; xg2 = xr[1024]; xg3 = xr[1536];
      asm volatile("" : "+v"(xg0), "+v"(xg1), "+v"(xg2), "+v"(xg3));
    }
    // ---- poll own A-frag packets (tags self-validating) ----
    const char* ap = hexd + par*32768 + m*2048 + w*256 + hi*32;
    u32x4 d0, d1, d2, d3;
    const unsigned expt = (unsigned)step;
    unsigned spin = 0;
    for (;;){
      asm volatile("global_load_dwordx4 %0, %1, off sc0 sc1" : "=v"(d0) : "v"(ap));
      asm volatile("global_load_dwordx4 %0, %1, off offset:16 sc0 sc1" : "=v"(d1) : "v"(ap));
      asm volatile("global_load_dwordx4 %0, %1, off offset:128 sc0 sc1" : "=v"(d2) : "v"(ap));
      asm volatile("global_load_dwordx4 %0, %1, off offset:144 sc0 sc1" : "=v"(d3) : "v"(ap));
      asm volatile("s_waitcnt vmcnt(0)" ::: "memory");
      unsigned bad = (d0[1]^expt)|(d0[3]^expt)|(d1[1]^expt)|(d1[3]^expt)
                   | (d2[1]^expt)|(d2[3]^expt)|(d3[1]^expt)|(d3[3]^expt);
      if (__all(bad == 0u)) break;
      if (++spin > 65536u) break;            // bounded-spin escape (fail clean)
      __builtin_amdgcn_s_sleep(1);
    }
    __builtin_amdgcn_sched_barrier(0);
    // strip tags -> A-frags
    union { unsigned int u[4]; short8 s; } a0, a1;
    a0.u[0]=d0[0]; a0.u[1]=d0[2]; a0.u[2]=d1[0]; a0.u[3]=d1[2];
    a1.u[0]=d2[0]; a1.u[1]=d2[2]; a1.u[2]=d3[0]; a1.u[3]=d3[2];
    f32x4 acc[4] = {{0.f,0.f,0.f,0.f},{0.f,0.f,0.f,0.f},{0.f,0.f,0.f,0.f},{0.f,0.f,0.f,0.f}};
    #pragma unroll
    for (int nt = 0; nt < 4; nt++){
      acc[nt] = __builtin_amdgcn_mfma_f32_16x16x32_bf16(a0.s, bfr[nt][0], acc[nt], 0,0,0);
      acc[nt] = __builtin_amdgcn_mfma_f32_16x16x32_bf16(a1.s, bfr[nt][1], acc[nt], 0,0,0);
    }
    #pragma unroll
    for (int nt = 0; nt < 4; nt++)
      #pragma unroll
      for (int r = 0; r < 4; r++)
        z_s[par][w][hi*4 + r][nt*16 + m] = acc[nt][r];
    __syncthreads();                  // single barrier per step
    if (t < 256){
      float z0 = xg0, z1 = xg1, z2 = xg2, z3 = xg3;
      #pragma unroll
      for (int ke = 0; ke < 8; ke++){
        z0 += z_s[par][ke][eb][eu];
        z1 += z_s[par][ke][eb][16 + eu];
        z2 += z_s[par][ke][eb][32 + eu];
        z3 += z_s[par][ke][eb][48 + eu];
      }
      creg = sigf(z2 + 1.f)*creg + sigf(z0)*tanhf(z1);
      float hh = sigf(z3)*tanhf(creg);
      unsigned int hb16 = (unsigned int)f2bf(hh);
      unsigned int nb = (unsigned int)__shfl_xor((int)hb16, 1);
      if (!(eu & 1)){
        unsigned long long pkt = (unsigned long long)((hb16 & 0xffffu) | (nb << 16))
                               | ((unsigned long long)(unsigned)(step+1) << 32);
        __hip_atomic_store((unsigned long long*)(hexd + (par^1)*32768 + eb*2048 + (u0 + eu)*4),
                           pkt, __ATOMIC_RELAXED, __HIP_MEMORY_SCOPE_AGENT);
      }
      Hcat_h[((long long)eb*J_ + t_eff)*1024 + dir*512 + u0 + eu] = (unsigned short)hb16;
    }
  }
}

// gathered-logits + word emission: one 16x16 tile per block, 64 thr.
__global__ __launch_bounds__(64, 8) void k_glgemm(
    const unsigned short* __restrict__ t1h,   // [1536][512]
    const unsigned short* __restrict__ WvT,   // [32000][512]
    const float* __restrict__ bv,
    const int* __restrict__ sources,          // [16][96]
    const float* __restrict__ rowsum,         // [1536]
    float* __restrict__ out_em)               // [16][192][96]
{
  const int bx = blockIdx.x;                  // 16 b x 36 tiles
  const int b = bx / 36, tile = bx % 36;
  const int mt = tile / 6, nt = tile % 6;
  const int lane = threadIdx.x;
  const int rr = lane & 15, kq = lane >> 4;
  int s = sources[b*96 + nt*16 + rr];
  float bg = bv[s];
  const unsigned short* arow = t1h + ((long long)(b*96 + mt*16 + rr))*512 + kq*8;
  const unsigned short* brow = WvT + (long long)s*512 + kq*8;
  f32x4 acc = {0.f,0.f,0.f,0.f};
  #pragma unroll
  for (int kc = 0; kc < 16; kc++){
    short8 af = *(const short8*)(arow + kc*32);
    short8 bf = *(const short8*)(brow + kc*32);
    acc = __builtin_amdgcn_mfma_f32_16x16x32_bf16(af, bf, acc, 0, 0, 0);
  }
  #pragma unroll
  for (int r = 0; r < 4; r++){
    int j = mt*16 + kq*4 + r;
    int i = nt*16 + rr;
    float v = __expf(acc[r] + bg) / rowsum[b*96 + j];
    out_em[((long long)b*192 + j)*96 + i] = v;
  }
}

// null half of emission: 96 identical rows per batch
__global__ void k_emission_null(const float* __restrict__ lognull,
                                const float* __restrict__ nullsum,
                                const int* __restrict__ sources,
                                float* __restrict__ out_em){
  int b = blockIdx.x;
  int i = threadIdx.x;
  if (i >= 96) return;
  int s = sources[b*96 + i];
  float v = __expf(lognull[s]) / nullsum[0];
  for (int jj = 0; jj < 96; jj++)
    out_em[((long long)b*192 + 96 + jj)*96 + i] = v;
}

__global__ void k_transition(const float* __restrict__ jlog, const float* __restrict__ p0p,
                             float* __restrict__ T, float* __restrict__ TL){
  int bx = blockIdx.x;           // b*J_ + j
  int b = bx / J_, j = bx % J_;
  int tid = threadIdx.x;         // 128
  __shared__ float ex[128];
  __shared__ float red[128];
  float e = 0.f;
  if (tid < 96) e = __expf(jlog[(long long)bx*SJ_ + (96 - j + tid)]);
  ex[tid] = e; red[tid] = e;
  __syncthreads();
  for (int w = 64; w > 0; w >>= 1){
    if (tid < w) red[tid] += red[tid+w];
    __syncthreads();
  }
  float p0 = p0p[0];
  float scale = (1.f - p0) / red[0];
  float lp0 = logf(p0);
  long long r0 = ((long long)b*192 + j)*192;
  long long r1 = ((long long)b*192 + j + 96)*192;
  for (int col = tid; col < 192; col += 128){
    float tv, lv;
    if (col < 96){ tv = ex[col]*scale; lv = logf(tv); }
    else { bool d = (col - 96) == j; tv = d ? p0 : 0.f; lv = d ? lp0 : 0.f; }
    T[r0 + col] = tv; T[r1 + col] = tv;
    TL[r0 + col] = lv; TL[r1 + col] = lv;
  }
}

extern "C" void kernel_launch(void* const* d_in, const int* in_sizes, int n_in,
                              void* d_out, int out_size, void* d_ws, size_t ws_size,
                              hipStream_t stream)
{
  const int* sources = (const int*)d_in[0];
  const int* targets = (const int*)d_in[1];
  const int* tnull   = (const int*)d_in[2];
  const float* emb   = (const float*)d_in[3];
  const float* Wfw   = (const float*)d_in[4];
  const float* bfw   = (const float*)d_in[5];
  const float* Wbw   = (const float*)d_in[6];
  const float* bbw   = (const float*)d_in[7];
  const float* Wl    = (const float*)d_in[8];
  const float* W1    = (const float*)d_in[9];
  const float* b1    = (const float*)d_in[10];
  const float* Wv    = (const float*)d_in[11];
  const float* bv    = (const float*)d_in[12];
  const float* Wj    = (const float*)d_in[13];
  const float* bj    = (const float*)d_in[14];
  const float* Wp    = (const float*)d_in[15];
  const float* bp    = (const float*)d_in[16];
  float* out = (float*)d_out;
  float* ws  = (float*)d_ws;

  long long off = 0;
  float* Xfw    = ws + off; off += (long long)NROW*2048;
  float* Xbw    = ws + off; off += (long long)NROW*2048;
  unsigned short* e_word_h = (unsigned short*)(ws + off); off += (long long)NROW*E_/2;
  unsigned short* WT       = (unsigned short*)(ws + off); off += 2LL*2048*256/2;
  unsigned short* Hcat_h   = (unsigned short*)(ws + off); off += (long long)NROW*1024/2;
  unsigned int* hex32 = (unsigned int*)(ws + off); off += 32768;  // [2dir][2par][16][256pkt u64]
  unsigned short* t1h = (unsigned short*)(ws + off); off += (long long)NROW*H_/2;
  unsigned short* W_comboT = (unsigned short*)(ws + off); off += 512LL*1024/2;
  unsigned short* WjT      = (unsigned short*)(ws + off); off += 256LL*512/2;
  float* rowsum = ws + off; off += NROW;
  float* nullsum= ws + off; off += 1;
  float* p0     = ws + off; off += 1;
  float* lognull= ws + off; off += VS_;
  float* jlog   = ws + off; off += (long long)NROW*SJ_;
  unsigned short* WvT = (unsigned short*)(ws + off); off += (long long)VS_*H_/2;

  float* out_em = out;
  float* out_T  = out + (long long)B_*192*96;
  float* out_TL = out_T + (long long)B_*192*192;

  // init: tagged h-exchange (tags reset each call), rowsum + nullsum
  k_init<<<128, 256, 0, stream>>>(hex32, rowsum);

  k_embed<<<NROW, 256, 0, stream>>>(targets, emb, e_word_h);
  k_wtr2<<<dim3(128, 2), 512, 0, stream>>>(Wfw, Wbw, WT);

  // input projections (bf16 MFMA): X = e_word @ W[:256] + b, fp32 out
  k_bgemm<0><<<192, 256, 0, stream>>>(e_word_h, WT,            E_, 2048, bfw, Xfw, nullptr, 2048, nullptr);
  k_bgemm<0><<<192, 256, 0, stream>>>(e_word_h, WT + 2048*256, E_, 2048, bbw, Xbw, nullptr, 2048, nullptr);

  // fused persistent tagged-packet bi-LSTM + side work
  k_fused<<<4288, 512, 0, stream>>>(Xfw, Xbw, Wfw, Wbw, hex32, Hcat_h,
                                    tnull, emb, W1, b1, Wp, bp, Wv, bv,
                                    WvT, lognull, nullsum, p0,
                                    Wl, W_comboT, Wj, WjT);

  // t1h = bf16(tanh(Hcat @ (Wl@W1) + b1))   [1536,1024]@[1024,512]
  k_bgemm<2><<<48, 256, 0, stream>>>(Hcat_h, W_comboT, 2*H_, H_, b1, nullptr, t1h, H_, nullptr);

  // jump logits (bf16 MFMA, N-guarded): [1536,512]@[512,193] + bj
  k_bgemm<0><<<24, 256, 0, stream>>>(t1h, WjT, H_, SJ_, bj, jlog, nullptr, SJ_, nullptr);

  // rowsum[m] = sum_n exp(logits) via bf16 MFMA GEMM
  k_bgemm<3><<<3000, 256, 0, stream>>>(t1h, WvT, H_, VS_, bv, nullptr, nullptr, VS_, rowsum);

  // gathered logits + word emission (fused), 576 blocks
  k_glgemm<<<576, 64, 0, stream>>>(t1h, WvT, bv, sources, rowsum, out_em);

  k_emission_null<<<B_, 128, 0, stream>>>(lognull, nullsum, sources, out_em);
  k_transition<<<NROW, 128, 0, stream>>>(jlog, p0, out_T, out_TL);
}